// Round 9
// baseline (892.999 us; speedup 1.0000x reference)
//
#include <hip/hip_runtime.h>
#include <hip/hip_bf16.h>
#include <math.h>

typedef __bf16 bf16x8 __attribute__((ext_vector_type(8)));
typedef float  f32x4  __attribute__((ext_vector_type(4)));
typedef unsigned int u32x4 __attribute__((ext_vector_type(4)));
typedef __hip_bfloat16 bf16_t;

static constexpr int C_    = 128;
static constexpr int L_    = 56 * 56;        // tokens per image
static constexpr int M_    = 64 * L_;        // 200704 total tokens
static constexpr int NWIN  = 64 * 64;        // 4096 windows
static constexpr int VSTR  = 56;             // vT padded key stride

// map windowed token index tw -> unwindowed token index (shift+window bijection)
__device__ inline long win_to_tok(int tw)
{
    int win = tw / 49, n = tw % 49;
    int bb  = win >> 6, wi = win & 63;
    int wh  = wi >> 3, wwp = wi & 7;
    int hs  = wh * 7 + n / 7;
    int wsv = wwp * 7 + n % 7;
    int hh  = (hs + 3) % 56;          // un-shift
    int ww  = (wsv + 3) % 56;
    return (long)bb * L_ + hh * 56 + ww;
}

__device__ inline unsigned int pk2(float lo, float hi)
{
    unsigned short a = __builtin_bit_cast(unsigned short, (__bf16)lo);
    unsigned short b = __builtin_bit_cast(unsigned short, (__bf16)hi);
    return (unsigned int)a | ((unsigned int)b << 16);
}

// tanh-form GELU: x * sigmoid(2u), u = 0.79788456 x (1 + 0.044715 x^2).
// ~7 VALU ops, no branches; |err| <= ~3e-3 (threshold is 0.11).
__device__ inline float gelu_f(float x)
{
    float u = 0.7978845608f * x * (1.f + 0.044715f * x * x);
    float e = __expf(2.f * fminf(u, 15.f));   // u<<0: e->0 -> gelu->0; u>15: ->x
    return x * e * __builtin_amdgcn_rcpf(e + 1.f);
}

__global__ void sentinel_kernel(float* o) { o[threadIdx.x] = 1e9f; }

// ---------------------------------------------------------------------------
__global__ void transpose_w(const float* __restrict__ w, bf16_t* __restrict__ wt,
                            int K, int N)
{
    int i = blockIdx.x * 256 + threadIdx.x;
    if (i >= K * N) return;
    int k = i / N, n = i % N;
    wt[(long)n * K + k] = __float2bfloat16(w[i]);
}

// zero vT pad keys 49..55 for all (win, d)
__global__ void zpad_kernel(bf16_t* __restrict__ vT)
{
    long i = (long)blockIdx.x * 256 + threadIdx.x;
    if (i >= (long)NWIN * 128 * 7) return;
    long row = i / 7;
    int  k   = 49 + (int)(i % 7);
    vT[row * VSTR + k] = __float2bfloat16(0.f);
}

// ---------------------------------------------------------------------------
// GEMM, one wave = 64x64 output tile. Block = 4 waves stacked in M (256 rows).
// grid = (M/256, N/64).
// LNM: 0 = A is plain bf16 row-major
//      1 = A = LN1(gather shifted/windowed row of x f32)   [qkv]
// EPI: 0 = qkv: cols<256 -> qk[token][256]; cols>=256 -> vT[win][d][key]
//      1 = proj: window-reverse + unshift + x(f32) residual -> f32 out
// ---------------------------------------------------------------------------
template<int K, int N, int LNM, int EPI>
__global__ __launch_bounds__(256) void gemm2(const void*  __restrict__ Asrc,
                                             const float* __restrict__ lng,
                                             const float* __restrict__ lnb,
                                             const bf16_t* __restrict__ Bt,
                                             const float*  __restrict__ bias,
                                             void*         outp,
                                             const float*  resf,
                                             bf16_t*       vTp)
{
    int lane = threadIdx.x & 63;
    int wave = threadIdx.x >> 6;
    int la = lane & 15, lb = lane >> 4;
    int m0   = (blockIdx.x * 4 + wave) * 64;
    int c0   = blockIdx.y * 64;

    f32x4 acc[4][4];
#pragma unroll
    for (int nt = 0; nt < 4; ++nt) {
        float bv = bias[c0 + nt * 16 + la];
#pragma unroll
        for (int s = 0; s < 4; ++s) acc[s][nt] = (f32x4){bv, bv, bv, bv};
    }

    static_assert(K == 128, "gemm2 is K=128 only now");
    bf16x8 areg[4][4];
    if constexpr (LNM == 0) {
#pragma unroll
        for (int s = 0; s < 4; ++s)
#pragma unroll
            for (int kt = 0; kt < 4; ++kt)
                areg[s][kt] = *reinterpret_cast<const bf16x8*>(
                    (const bf16_t*)Asrc + (long)(m0 + s * 16 + la) * K + kt * 32 + lb * 8);
    } else {
#pragma unroll
        for (int s = 0; s < 4; ++s) {
            long src = win_to_tok(m0 + s * 16 + la);
            const float* xr = (const float*)Asrc + src * C_;
            float vals[4][8];
            float sm = 0.f, qs = 0.f;
#pragma unroll
            for (int kt = 0; kt < 4; ++kt) {
                f32x4 u0 = *reinterpret_cast<const f32x4*>(xr + kt * 32 + lb * 8);
                f32x4 u1 = *reinterpret_cast<const f32x4*>(xr + kt * 32 + lb * 8 + 4);
#pragma unroll
                for (int j = 0; j < 4; ++j) { vals[kt][j] = u0[j]; vals[kt][4 + j] = u1[j]; }
#pragma unroll
                for (int j = 0; j < 8; ++j) { sm += vals[kt][j]; qs += vals[kt][j] * vals[kt][j]; }
            }
            sm += __shfl_xor(sm, 16); sm += __shfl_xor(sm, 32);
            qs += __shfl_xor(qs, 16); qs += __shfl_xor(qs, 32);
            float mean = sm * (1.f / 128.f);
            float rstd = rsqrtf(qs * (1.f / 128.f) - mean * mean + 1e-5f);
#pragma unroll
            for (int kt = 0; kt < 4; ++kt)
#pragma unroll
                for (int j = 0; j < 8; ++j) {
                    int col = kt * 32 + lb * 8 + j;
                    areg[s][kt][j] = (__bf16)((vals[kt][j] - mean) * rstd * lng[col] + lnb[col]);
                }
        }
    }

    bf16x8 breg[4][4];
#pragma unroll
    for (int kt = 0; kt < 4; ++kt)
#pragma unroll
        for (int nt = 0; nt < 4; ++nt)
            breg[kt][nt] = *reinterpret_cast<const bf16x8*>(
                Bt + (long)(c0 + nt * 16 + la) * K + kt * 32 + lb * 8);
#pragma unroll
    for (int kt = 0; kt < 4; ++kt)
#pragma unroll
        for (int nt = 0; nt < 4; ++nt)
#pragma unroll
            for (int s = 0; s < 4; ++s)
                acc[s][nt] = __builtin_amdgcn_mfma_f32_16x16x32_bf16(
                    areg[s][kt], breg[kt][nt], acc[s][nt], 0, 0, 0);

#pragma unroll
    for (int s = 0; s < 4; ++s) {
#pragma unroll
        for (int r = 0; r < 4; ++r) {
            int row = m0 + s * 16 + lb * 4 + r;
            if constexpr (EPI == 0) {
                int win = row / 49, key = row - win * 49;
#pragma unroll
                for (int nt = 0; nt < 4; ++nt) {
                    int col = c0 + nt * 16 + la;
                    float v = acc[s][nt][r];
                    if (col < 256)
                        ((bf16_t*)outp)[(long)row * 256 + col] = __float2bfloat16(v);
                    else
                        vTp[((long)win * 128 + (col - 256)) * VSTR + key] = __float2bfloat16(v);
                }
            } else {
                long to = win_to_tok(row);
#pragma unroll
                for (int nt = 0; nt < 4; ++nt) {
                    int col = c0 + nt * 16 + la;
                    ((float*)outp)[to * C_ + col] = acc[s][nt][r] + resf[to * C_ + col];
                }
            }
        }
    }
}

// ---------------------------------------------------------------------------
// MFMA windowed attention: one block per window, one wave per head. No LDS.
// ---------------------------------------------------------------------------
__global__ __launch_bounds__(256) void attn_mfma(const bf16_t* __restrict__ qk,
                                                 const bf16_t* __restrict__ vT,
                                                 const float*  __restrict__ rpb,
                                                 bf16_t* __restrict__ out)
{
    int win  = blockIdx.x;
    int h    = threadIdx.x >> 6;
    int lane = threadIdx.x & 63;
    int la = lane & 15, lb = lane >> 4;

    const bf16_t* qkw = qk + (long)win * 49 * 256;

    bf16x8 kf[4], qf[4];
#pragma unroll
    for (int t = 0; t < 4; ++t) {
        kf[t] = *reinterpret_cast<const bf16x8*>(qkw + (long)(t * 16 + la) * 256 + 128 + h * 32 + lb * 8);
        qf[t] = *reinterpret_cast<const bf16x8*>(qkw + (long)(t * 16 + la) * 256 +       h * 32 + lb * 8);
    }

    f32x4 S[4][4];
#pragma unroll
    for (int qt = 0; qt < 4; ++qt)
#pragma unroll
        for (int kt = 0; kt < 4; ++kt)
            S[qt][kt] = __builtin_amdgcn_mfma_f32_16x16x32_bf16(
                kf[kt], qf[qt], (f32x4){0.f, 0.f, 0.f, 0.f}, 0, 0, 0);

    const float scale = 0.17677669529663687f;   // 1/sqrt(32)
    int wi  = win & 63;
    int wh  = wi >> 3, wwp = wi & 7;
    bool edge = (wh == 7) || (wwp == 7);

    int i1[4], j1[4], r1[4], c1[4];
#pragma unroll
    for (int qt = 0; qt < 4; ++qt) {
        int q  = qt * 16 + la;
        int qc = q < 49 ? q : 48;
        i1[qt] = qc / 7; j1[qt] = qc - 7 * i1[qt];
        r1[qt] = (wh  < 7) ? 0 : ((i1[qt] < 4) ? 1 : 2);
        c1[qt] = (wwp < 7) ? 0 : ((j1[qt] < 4) ? 1 : 2);
    }

#pragma unroll
    for (int kt = 0; kt < 4; ++kt) {
#pragma unroll
        for (int r = 0; r < 4; ++r) {
            if (kt == 3 && r > 0) {
#pragma unroll
                for (int qt = 0; qt < 4; ++qt) S[qt][kt][r] = -1e30f;
                continue;
            }
            int key = kt * 16 + lb * 4 + r;
            int kc  = key < 49 ? key : 48;
            int i2  = kc / 7, j2 = kc - 7 * i2;
            int r2  = (wh  < 7) ? 0 : ((i2 < 4) ? 1 : 2);
            int c2  = (wwp < 7) ? 0 : ((j2 < 4) ? 1 : 2);
#pragma unroll
            for (int qt = 0; qt < 4; ++qt) {
                float bv  = rpb[(((i1[qt] - i2 + 6) * 13 + (j1[qt] - j2 + 6)) << 2) + h];
                float val = S[qt][kt][r] * scale + bv;
                if (edge && ((r1[qt] != r2) | (c1[qt] != c2))) val -= 100.f;
                if (kt == 3 && lb > 0) val = -1e30f;
                S[qt][kt][r] = val;
            }
        }
    }

    float inv[4];
#pragma unroll
    for (int qt = 0; qt < 4; ++qt) {
        float mx = -3e38f;
#pragma unroll
        for (int kt = 0; kt < 4; ++kt)
#pragma unroll
            for (int r = 0; r < 4; ++r) mx = fmaxf(mx, S[qt][kt][r]);
        mx = fmaxf(mx, __shfl_xor(mx, 16));
        mx = fmaxf(mx, __shfl_xor(mx, 32));
        float sm = 0.f;
#pragma unroll
        for (int kt = 0; kt < 4; ++kt)
#pragma unroll
            for (int r = 0; r < 4; ++r) {
                float e = __expf(S[qt][kt][r] - mx);
                S[qt][kt][r] = e;
                sm += e;
            }
        sm += __shfl_xor(sm, 16);
        sm += __shfl_xor(sm, 32);
        inv[qt] = 1.f / sm;
    }

    unsigned int w_[4][4][2];
#pragma unroll
    for (int qt = 0; qt < 4; ++qt)
#pragma unroll
        for (int t = 0; t < 4; ++t) {
            w_[qt][t][0] = pk2(S[qt][t][0], S[qt][t][1]);
            w_[qt][t][1] = pk2(S[qt][t][2], S[qt][t][3]);
        }

    int srcA = la + (((2 * lb)     & 3) << 4);
    int srcB = la + (((2 * lb + 1) & 3) << 4);
    bool hiT = (lb >> 1) & 1;

    f32x4 O[2][4];
#pragma unroll
    for (int dt = 0; dt < 2; ++dt)
#pragma unroll
        for (int qt = 0; qt < 4; ++qt) O[dt][qt] = (f32x4){0.f, 0.f, 0.f, 0.f};

    const bf16_t* vrow = vT + ((long)win * 128 + h * 32) * VSTR;
#pragma unroll
    for (int kk = 0; kk < 2; ++kk) {
        bf16x8 vf[2];
#pragma unroll
        for (int dt = 0; dt < 2; ++dt)
            vf[dt] = *reinterpret_cast<const bf16x8*>(
                vrow + (long)(dt * 16 + la) * VSTR + kk * 32 + lb * 8);
        int tl = kk * 2;
#pragma unroll
        for (int qt = 0; qt < 4; ++qt) {
            unsigned int a0 = __shfl(w_[qt][tl][0],     srcA);
            unsigned int b0 = __shfl(w_[qt][tl + 1][0], srcA);
            unsigned int a1 = __shfl(w_[qt][tl][1],     srcA);
            unsigned int b1 = __shfl(w_[qt][tl + 1][1], srcA);
            unsigned int a2 = __shfl(w_[qt][tl][0],     srcB);
            unsigned int b2 = __shfl(w_[qt][tl + 1][0], srcB);
            unsigned int a3 = __shfl(w_[qt][tl][1],     srcB);
            unsigned int b3 = __shfl(w_[qt][tl + 1][1], srcB);
            u32x4 uu = { hiT ? b0 : a0, hiT ? b1 : a1, hiT ? b2 : a2, hiT ? b3 : a3 };
            bf16x8 pf = __builtin_bit_cast(bf16x8, uu);
#pragma unroll
            for (int dt = 0; dt < 2; ++dt)
                O[dt][qt] = __builtin_amdgcn_mfma_f32_16x16x32_bf16(vf[dt], pf, O[dt][qt], 0, 0, 0);
        }
    }

    bf16_t* ob = out + (long)win * 49 * C_ + h * 32;
#pragma unroll
    for (int qt = 0; qt < 4; ++qt) {
        int q = qt * 16 + la;
        if (q < 49) {
            float iv = inv[qt];
#pragma unroll
            for (int dt = 0; dt < 2; ++dt) {
                unsigned int s0 = pk2(O[dt][qt][0] * iv, O[dt][qt][1] * iv);
                unsigned int s1 = pk2(O[dt][qt][2] * iv, O[dt][qt][3] * iv);
                uint2 st = {s0, s1};
                *reinterpret_cast<uint2*>(ob + (long)q * C_ + dt * 16 + lb * 4) = st;
            }
        }
    }
}

// ---------------------------------------------------------------------------
// Fused MLP v4: out = y + fc2(gelu(fc1(LN2(y)))).  One wave = 16 rows.
// No LDS, no barriers. Software-pipelined: FC1(c+1) issues between FC1(c)
// and FC2(c) (named double buffers haccA/haccB). Fast tanh-GELU.
// fc1 TRANSPOSED: hT = mfma(A=W1t rows, B=af) -> hidden in (nt, lb*4+r),
// m in la (the verified attention repack source layout). The attention
// shuffle builds fc2 B-fragments; A = W2t rows. out^T acc, f32x4 stores.
// ---------------------------------------------------------------------------
__global__ __launch_bounds__(256) void mlp_fused(const float* __restrict__ y,
                                                 const float* __restrict__ g,
                                                 const float* __restrict__ b,
                                                 const bf16_t* __restrict__ w1t,
                                                 const float* __restrict__ b1,
                                                 const bf16_t* __restrict__ w2t,
                                                 const float* __restrict__ b2,
                                                 float* __restrict__ out)
{
    int lane = threadIdx.x & 63;
    int la = lane & 15, lb = lane >> 4;
    int m0 = (blockIdx.x * 4 + (threadIdx.x >> 6)) * 16;

    // ---- LN2 of row m0+la -> af[4] (m = la, k = kt*32+lb*8+j) ----
    const float* yr = y + (long)(m0 + la) * C_;
    bf16x8 af[4];
    {
        float vals[4][8];
        float sm = 0.f, qs = 0.f;
#pragma unroll
        for (int kt = 0; kt < 4; ++kt) {
            f32x4 u0 = *reinterpret_cast<const f32x4*>(yr + kt * 32 + lb * 8);
            f32x4 u1 = *reinterpret_cast<const f32x4*>(yr + kt * 32 + lb * 8 + 4);
#pragma unroll
            for (int j = 0; j < 4; ++j) { vals[kt][j] = u0[j]; vals[kt][4 + j] = u1[j]; }
#pragma unroll
            for (int j = 0; j < 8; ++j) { sm += vals[kt][j]; qs += vals[kt][j] * vals[kt][j]; }
        }
        sm += __shfl_xor(sm, 16); sm += __shfl_xor(sm, 32);
        qs += __shfl_xor(qs, 16); qs += __shfl_xor(qs, 32);
        float mean = sm * (1.f / 128.f);
        float rstd = rsqrtf(qs * (1.f / 128.f) - mean * mean + 1e-5f);
#pragma unroll
        for (int kt = 0; kt < 4; ++kt)
#pragma unroll
            for (int j = 0; j < 8; ++j) {
                int col = kt * 32 + lb * 8 + j;
                af[kt][j] = (__bf16)((vals[kt][j] - mean) * rstd * g[col] + b[col]);
            }
    }

    // ---- out^T accumulators: acc[nt2]: out[m=la(+m0)][n2=nt2*16+lb*4+r] ----
    f32x4 acc[8];
#pragma unroll
    for (int nt2 = 0; nt2 < 8; ++nt2)
        acc[nt2] = *reinterpret_cast<const f32x4*>(b2 + nt2 * 16 + lb * 4);

    int srcA = la + (((2 * lb)     & 3) << 4);
    int srcB = la + (((2 * lb + 1) & 3) << 4);
    bool hiT = (lb >> 1) & 1;

    f32x4 haccA[4], haccB[4];

    // fc1 chunk c (transposed): hacc[nt][r] = hT[n1=c*64+nt*16+lb*4+r][m=la]
    auto FC1 = [&](int c, f32x4 (&hacc)[4]) {
#pragma unroll
        for (int nt = 0; nt < 4; ++nt)
            hacc[nt] = *reinterpret_cast<const f32x4*>(b1 + c * 64 + nt * 16 + lb * 4);
#pragma unroll
        for (int kt = 0; kt < 4; ++kt)
#pragma unroll
            for (int nt = 0; nt < 4; ++nt) {
                bf16x8 w1f = *reinterpret_cast<const bf16x8*>(
                    w1t + (long)(c * 64 + nt * 16 + la) * 128 + kt * 32 + lb * 8);
                hacc[nt] = __builtin_amdgcn_mfma_f32_16x16x32_bf16(
                    w1f, af[kt], hacc[nt], 0, 0, 0);
            }
    };

    // fc2 chunk c: GELU -> pack -> attention-shuffle -> 16 MFMA into acc
    auto FC2 = [&](int c, f32x4 (&hacc)[4]) {
        bf16x8 w2f[8];                      // kk=0 fragments (data-independent)
#pragma unroll
        for (int nt2 = 0; nt2 < 8; ++nt2)
            w2f[nt2] = *reinterpret_cast<const bf16x8*>(
                w2t + (long)(nt2 * 16 + la) * 512 + c * 64 + lb * 8);
        unsigned int wpk[4][2];
#pragma unroll
        for (int t = 0; t < 4; ++t) {
            f32x4 hv = hacc[t];
#pragma unroll
            for (int r = 0; r < 4; ++r) hv[r] = gelu_f(hv[r]);
            wpk[t][0] = pk2(hv[0], hv[1]);
            wpk[t][1] = pk2(hv[2], hv[3]);
        }
#pragma unroll
        for (int kk = 0; kk < 2; ++kk) {
            if (kk == 1) {
#pragma unroll
                for (int nt2 = 0; nt2 < 8; ++nt2)
                    w2f[nt2] = *reinterpret_cast<const bf16x8*>(
                        w2t + (long)(nt2 * 16 + la) * 512 + c * 64 + 32 + lb * 8);
            }
            int tl = kk * 2;
            unsigned int a0 = __shfl(wpk[tl][0],     srcA);
            unsigned int b0 = __shfl(wpk[tl + 1][0], srcA);
            unsigned int a1 = __shfl(wpk[tl][1],     srcA);
            unsigned int b1v = __shfl(wpk[tl + 1][1], srcA);
            unsigned int a2 = __shfl(wpk[tl][0],     srcB);
            unsigned int b2v = __shfl(wpk[tl + 1][0], srcB);
            unsigned int a3 = __shfl(wpk[tl][1],     srcB);
            unsigned int b3v = __shfl(wpk[tl + 1][1], srcB);
            u32x4 uu = { hiT ? b0 : a0, hiT ? b1v : a1, hiT ? b2v : a2, hiT ? b3v : a3 };
            bf16x8 pf = __builtin_bit_cast(bf16x8, uu);
#pragma unroll
            for (int nt2 = 0; nt2 < 8; ++nt2)
                acc[nt2] = __builtin_amdgcn_mfma_f32_16x16x32_bf16(
                    w2f[nt2], pf, acc[nt2], 0, 0, 0);
        }
    };

    // ---- software pipeline: FC1 runs one chunk ahead of FC2 ----
    FC1(0, haccA);
    FC1(1, haccB);
    FC2(0, haccA);
    FC1(2, haccA);
    FC2(1, haccB);
    FC1(3, haccB);
    FC2(2, haccA);
    FC1(4, haccA);
    FC2(3, haccB);
    FC1(5, haccB);
    FC2(4, haccA);
    FC1(6, haccA);
    FC2(5, haccB);
    FC1(7, haccB);
    FC2(6, haccA);
    FC2(7, haccB);

    // ---- epilogue: + y residual -> out (in-place safe: exclusive rows) ----
    {
        long m = m0 + la;
        const float* yrow = y + m * C_;
        float* orow = out + m * C_;
#pragma unroll
        for (int nt2 = 0; nt2 < 8; ++nt2) {
            int n2 = nt2 * 16 + lb * 4;
            f32x4 res = *reinterpret_cast<const f32x4*>(yrow + n2);
            f32x4 val = acc[nt2] + res;
            *reinterpret_cast<f32x4*>(orow + n2) = val;
        }
    }
}

// ---------------------------------------------------------------------------
extern "C" void kernel_launch(void* const* d_in, const int* in_sizes, int n_in,
                              void* d_out, int out_size, void* d_ws, size_t ws_size,
                              hipStream_t stream)
{
    (void)in_sizes; (void)n_in; (void)out_size;

    const float* x      = (const float*)d_in[0];
    const float* n1g    = (const float*)d_in[1];
    const float* n1b    = (const float*)d_in[2];
    const float* qkv_w  = (const float*)d_in[3];
    const float* qkv_b  = (const float*)d_in[4];
    const float* proj_w = (const float*)d_in[5];
    const float* proj_b = (const float*)d_in[6];
    const float* rpb    = (const float*)d_in[7];
    const float* n2g    = (const float*)d_in[8];
    const float* n2b    = (const float*)d_in[9];
    const float* fc1_w  = (const float*)d_in[10];
    const float* fc1_b  = (const float*)d_in[11];
    const float* fc2_w  = (const float*)d_in[12];
    const float* fc2_b  = (const float*)d_in[13];

    char* ws = (char*)d_ws;

    const size_t qk_sz = (size_t)M_ * 256 * 2;               // 102,760,448
    const size_t vt_sz = (size_t)NWIN * 128 * VSTR * 2;      //  58,720,256
    const size_t at_sz = (size_t)M_ * 128 * 2;               //  51,380,224
    const size_t w_off = qk_sz + vt_sz + at_sz;
    const size_t w_sz  = (size_t)(128 * 384 + 128 * 128 + 128 * 512 + 512 * 128) * 2;
    const size_t need  = w_off + w_sz;                       // ~213.6 MB

    if (need > ws_size) {
        sentinel_kernel<<<1, 256, 0, stream>>>((float*)d_out);
        return;
    }

    bf16_t* qkb  = (bf16_t*)ws;
    bf16_t* vT   = (bf16_t*)(ws + qk_sz);
    bf16_t* attb = (bf16_t*)(ws + qk_sz + vt_sz);
    bf16_t* qkv_wt  = (bf16_t*)(ws + w_off);
    bf16_t* proj_wt = qkv_wt + 128 * 384;
    bf16_t* fc1_wt  = proj_wt + 128 * 128;
    bf16_t* fc2_wt  = fc1_wt + 128 * 512;

    float* y = (float*)d_out;

    transpose_w<<<(128 * 384 + 255) / 256, 256, 0, stream>>>(qkv_w, qkv_wt, 128, 384);
    transpose_w<<<(128 * 128 + 255) / 256, 256, 0, stream>>>(proj_w, proj_wt, 128, 128);
    transpose_w<<<(128 * 512 + 255) / 256, 256, 0, stream>>>(fc1_w, fc1_wt, 128, 512);
    transpose_w<<<(512 * 128 + 255) / 256, 256, 0, stream>>>(fc2_w, fc2_wt, 512, 128);

    // zero vT pad keys (NaN safety for PV fragments)
    zpad_kernel<<<(NWIN * 128 * 7 + 255) / 256, 256, 0, stream>>>(vT);
    // LN1 + shift/window gather fused into QKV projection
    gemm2<128, 384, 1, 0><<<dim3(M_ / 256, 6), 256, 0, stream>>>(
        x, n1g, n1b, qkv_wt, qkv_b, qkb, nullptr, vT);
    // MFMA attention
    attn_mfma<<<NWIN, 256, 0, stream>>>(qkb, vT, rpb, attb);
    // proj + window-reverse + x residual -> f32 y (= d_out)
    gemm2<128, 128, 0, 1><<<dim3(M_ / 256, 2), 256, 0, stream>>>(
        attb, nullptr, nullptr, proj_wt, proj_b, y, x, nullptr);
    // fused LN2 + fc1 + GELU + fc2 + residual (in-place on d_out, no LDS)
    mlp_fused<<<M_ / 64, 256, 0, stream>>>(
        y, n2g, n2b, fc1_wt, fc1_b, fc2_wt, fc2_b, y);
}

// Round 10
// 795.372 us; speedup vs baseline: 1.1227x; 1.1227x over previous
//
#include <hip/hip_runtime.h>
#include <hip/hip_bf16.h>
#include <math.h>

typedef __bf16 bf16x8 __attribute__((ext_vector_type(8)));
typedef float  f32x4  __attribute__((ext_vector_type(4)));
typedef unsigned int u32x4 __attribute__((ext_vector_type(4)));
typedef __hip_bfloat16 bf16_t;

static constexpr int C_    = 128;
static constexpr int L_    = 56 * 56;        // tokens per image
static constexpr int M_    = 64 * L_;        // 200704 total tokens
static constexpr int NWIN  = 64 * 64;        // 4096 windows
static constexpr int VSTR  = 56;             // vT padded key stride

// map windowed token index tw -> unwindowed token index (shift+window bijection)
__device__ inline long win_to_tok(int tw)
{
    int win = tw / 49, n = tw % 49;
    int bb  = win >> 6, wi = win & 63;
    int wh  = wi >> 3, wwp = wi & 7;
    int hs  = wh * 7 + n / 7;
    int wsv = wwp * 7 + n % 7;
    int hh  = (hs + 3) % 56;          // un-shift
    int ww  = (wsv + 3) % 56;
    return (long)bb * L_ + hh * 56 + ww;
}

__device__ inline unsigned int pk2(float lo, float hi)
{
    unsigned short a = __builtin_bit_cast(unsigned short, (__bf16)lo);
    unsigned short b = __builtin_bit_cast(unsigned short, (__bf16)hi);
    return (unsigned int)a | ((unsigned int)b << 16);
}

// tanh-form GELU: x * sigmoid(2u), u = 0.79788456 x (1 + 0.044715 x^2).
// ~8 VALU ops, no branches; |err| <= ~3e-3 (threshold is 0.11).
__device__ inline float gelu_f(float x)
{
    float u = 0.7978845608f * x * (1.f + 0.044715f * x * x);
    float e = __expf(2.f * fminf(u, 15.f));   // u<<0: e->0 -> gelu->0; u>15: ->x
    return x * e * __builtin_amdgcn_rcpf(e + 1.f);
}

__global__ void sentinel_kernel(float* o) { o[threadIdx.x] = 1e9f; }

// ---------------------------------------------------------------------------
__global__ void transpose_w(const float* __restrict__ w, bf16_t* __restrict__ wt,
                            int K, int N)
{
    int i = blockIdx.x * 256 + threadIdx.x;
    if (i >= K * N) return;
    int k = i / N, n = i % N;
    wt[(long)n * K + k] = __float2bfloat16(w[i]);
}

// zero vT pad keys 49..55 for all (win, d)
__global__ void zpad_kernel(bf16_t* __restrict__ vT)
{
    long i = (long)blockIdx.x * 256 + threadIdx.x;
    if (i >= (long)NWIN * 128 * 7) return;
    long row = i / 7;
    int  k   = 49 + (int)(i % 7);
    vT[row * VSTR + k] = __float2bfloat16(0.f);
}

// ---------------------------------------------------------------------------
// GEMM, one wave = 64x64 output tile. Block = 4 waves stacked in M (256 rows).
// grid = (M/256, N/64).
// LNM: 0 = A is plain bf16 row-major
//      1 = A = LN1(gather shifted/windowed row of x f32)   [qkv]
// EPI: 0 = qkv: cols<256 -> qk[token][256]; cols>=256 -> vT[win][d][key]
//      1 = proj: window-reverse + unshift + x(f32) residual -> f32 out
// ---------------------------------------------------------------------------
template<int K, int N, int LNM, int EPI>
__global__ __launch_bounds__(256) void gemm2(const void*  __restrict__ Asrc,
                                             const float* __restrict__ lng,
                                             const float* __restrict__ lnb,
                                             const bf16_t* __restrict__ Bt,
                                             const float*  __restrict__ bias,
                                             void*         outp,
                                             const float*  resf,
                                             bf16_t*       vTp)
{
    int lane = threadIdx.x & 63;
    int wave = threadIdx.x >> 6;
    int la = lane & 15, lb = lane >> 4;
    int m0   = (blockIdx.x * 4 + wave) * 64;
    int c0   = blockIdx.y * 64;

    f32x4 acc[4][4];
#pragma unroll
    for (int nt = 0; nt < 4; ++nt) {
        float bv = bias[c0 + nt * 16 + la];
#pragma unroll
        for (int s = 0; s < 4; ++s) acc[s][nt] = (f32x4){bv, bv, bv, bv};
    }

    static_assert(K == 128, "gemm2 is K=128 only now");
    bf16x8 areg[4][4];
    if constexpr (LNM == 0) {
#pragma unroll
        for (int s = 0; s < 4; ++s)
#pragma unroll
            for (int kt = 0; kt < 4; ++kt)
                areg[s][kt] = *reinterpret_cast<const bf16x8*>(
                    (const bf16_t*)Asrc + (long)(m0 + s * 16 + la) * K + kt * 32 + lb * 8);
    } else {
#pragma unroll
        for (int s = 0; s < 4; ++s) {
            long src = win_to_tok(m0 + s * 16 + la);
            const float* xr = (const float*)Asrc + src * C_;
            float vals[4][8];
            float sm = 0.f, qs = 0.f;
#pragma unroll
            for (int kt = 0; kt < 4; ++kt) {
                f32x4 u0 = *reinterpret_cast<const f32x4*>(xr + kt * 32 + lb * 8);
                f32x4 u1 = *reinterpret_cast<const f32x4*>(xr + kt * 32 + lb * 8 + 4);
#pragma unroll
                for (int j = 0; j < 4; ++j) { vals[kt][j] = u0[j]; vals[kt][4 + j] = u1[j]; }
#pragma unroll
                for (int j = 0; j < 8; ++j) { sm += vals[kt][j]; qs += vals[kt][j] * vals[kt][j]; }
            }
            sm += __shfl_xor(sm, 16); sm += __shfl_xor(sm, 32);
            qs += __shfl_xor(qs, 16); qs += __shfl_xor(qs, 32);
            float mean = sm * (1.f / 128.f);
            float rstd = rsqrtf(qs * (1.f / 128.f) - mean * mean + 1e-5f);
#pragma unroll
            for (int kt = 0; kt < 4; ++kt)
#pragma unroll
                for (int j = 0; j < 8; ++j) {
                    int col = kt * 32 + lb * 8 + j;
                    areg[s][kt][j] = (__bf16)((vals[kt][j] - mean) * rstd * lng[col] + lnb[col]);
                }
        }
    }

    bf16x8 breg[4][4];
#pragma unroll
    for (int kt = 0; kt < 4; ++kt)
#pragma unroll
        for (int nt = 0; nt < 4; ++nt)
            breg[kt][nt] = *reinterpret_cast<const bf16x8*>(
                Bt + (long)(c0 + nt * 16 + la) * K + kt * 32 + lb * 8);
#pragma unroll
    for (int kt = 0; kt < 4; ++kt)
#pragma unroll
        for (int nt = 0; nt < 4; ++nt)
#pragma unroll
            for (int s = 0; s < 4; ++s)
                acc[s][nt] = __builtin_amdgcn_mfma_f32_16x16x32_bf16(
                    areg[s][kt], breg[kt][nt], acc[s][nt], 0, 0, 0);

#pragma unroll
    for (int s = 0; s < 4; ++s) {
#pragma unroll
        for (int r = 0; r < 4; ++r) {
            int row = m0 + s * 16 + lb * 4 + r;
            if constexpr (EPI == 0) {
                int win = row / 49, key = row - win * 49;
#pragma unroll
                for (int nt = 0; nt < 4; ++nt) {
                    int col = c0 + nt * 16 + la;
                    float v = acc[s][nt][r];
                    if (col < 256)
                        ((bf16_t*)outp)[(long)row * 256 + col] = __float2bfloat16(v);
                    else
                        vTp[((long)win * 128 + (col - 256)) * VSTR + key] = __float2bfloat16(v);
                }
            } else {
                long to = win_to_tok(row);
#pragma unroll
                for (int nt = 0; nt < 4; ++nt) {
                    int col = c0 + nt * 16 + la;
                    ((float*)outp)[to * C_ + col] = acc[s][nt][r] + resf[to * C_ + col];
                }
            }
        }
    }
}

// ---------------------------------------------------------------------------
// MFMA windowed attention: one block per window, one wave per head. No LDS.
// ---------------------------------------------------------------------------
__global__ __launch_bounds__(256) void attn_mfma(const bf16_t* __restrict__ qk,
                                                 const bf16_t* __restrict__ vT,
                                                 const float*  __restrict__ rpb,
                                                 bf16_t* __restrict__ out)
{
    int win  = blockIdx.x;
    int h    = threadIdx.x >> 6;
    int lane = threadIdx.x & 63;
    int la = lane & 15, lb = lane >> 4;

    const bf16_t* qkw = qk + (long)win * 49 * 256;

    bf16x8 kf[4], qf[4];
#pragma unroll
    for (int t = 0; t < 4; ++t) {
        kf[t] = *reinterpret_cast<const bf16x8*>(qkw + (long)(t * 16 + la) * 256 + 128 + h * 32 + lb * 8);
        qf[t] = *reinterpret_cast<const bf16x8*>(qkw + (long)(t * 16 + la) * 256 +       h * 32 + lb * 8);
    }

    f32x4 S[4][4];
#pragma unroll
    for (int qt = 0; qt < 4; ++qt)
#pragma unroll
        for (int kt = 0; kt < 4; ++kt)
            S[qt][kt] = __builtin_amdgcn_mfma_f32_16x16x32_bf16(
                kf[kt], qf[qt], (f32x4){0.f, 0.f, 0.f, 0.f}, 0, 0, 0);

    const float scale = 0.17677669529663687f;   // 1/sqrt(32)
    int wi  = win & 63;
    int wh  = wi >> 3, wwp = wi & 7;
    bool edge = (wh == 7) || (wwp == 7);

    int i1[4], j1[4], r1[4], c1[4];
#pragma unroll
    for (int qt = 0; qt < 4; ++qt) {
        int q  = qt * 16 + la;
        int qc = q < 49 ? q : 48;
        i1[qt] = qc / 7; j1[qt] = qc - 7 * i1[qt];
        r1[qt] = (wh  < 7) ? 0 : ((i1[qt] < 4) ? 1 : 2);
        c1[qt] = (wwp < 7) ? 0 : ((j1[qt] < 4) ? 1 : 2);
    }

#pragma unroll
    for (int kt = 0; kt < 4; ++kt) {
#pragma unroll
        for (int r = 0; r < 4; ++r) {
            if (kt == 3 && r > 0) {
#pragma unroll
                for (int qt = 0; qt < 4; ++qt) S[qt][kt][r] = -1e30f;
                continue;
            }
            int key = kt * 16 + lb * 4 + r;
            int kc  = key < 49 ? key : 48;
            int i2  = kc / 7, j2 = kc - 7 * i2;
            int r2  = (wh  < 7) ? 0 : ((i2 < 4) ? 1 : 2);
            int c2  = (wwp < 7) ? 0 : ((j2 < 4) ? 1 : 2);
#pragma unroll
            for (int qt = 0; qt < 4; ++qt) {
                float bv  = rpb[(((i1[qt] - i2 + 6) * 13 + (j1[qt] - j2 + 6)) << 2) + h];
                float val = S[qt][kt][r] * scale + bv;
                if (edge && ((r1[qt] != r2) | (c1[qt] != c2))) val -= 100.f;
                if (kt == 3 && lb > 0) val = -1e30f;
                S[qt][kt][r] = val;
            }
        }
    }

    float inv[4];
#pragma unroll
    for (int qt = 0; qt < 4; ++qt) {
        float mx = -3e38f;
#pragma unroll
        for (int kt = 0; kt < 4; ++kt)
#pragma unroll
            for (int r = 0; r < 4; ++r) mx = fmaxf(mx, S[qt][kt][r]);
        mx = fmaxf(mx, __shfl_xor(mx, 16));
        mx = fmaxf(mx, __shfl_xor(mx, 32));
        float sm = 0.f;
#pragma unroll
        for (int kt = 0; kt < 4; ++kt)
#pragma unroll
            for (int r = 0; r < 4; ++r) {
                float e = __expf(S[qt][kt][r] - mx);
                S[qt][kt][r] = e;
                sm += e;
            }
        sm += __shfl_xor(sm, 16);
        sm += __shfl_xor(sm, 32);
        inv[qt] = 1.f / sm;
    }

    unsigned int w_[4][4][2];
#pragma unroll
    for (int qt = 0; qt < 4; ++qt)
#pragma unroll
        for (int t = 0; t < 4; ++t) {
            w_[qt][t][0] = pk2(S[qt][t][0], S[qt][t][1]);
            w_[qt][t][1] = pk2(S[qt][t][2], S[qt][t][3]);
        }

    int srcA = la + (((2 * lb)     & 3) << 4);
    int srcB = la + (((2 * lb + 1) & 3) << 4);
    bool hiT = (lb >> 1) & 1;

    f32x4 O[2][4];
#pragma unroll
    for (int dt = 0; dt < 2; ++dt)
#pragma unroll
        for (int qt = 0; qt < 4; ++qt) O[dt][qt] = (f32x4){0.f, 0.f, 0.f, 0.f};

    const bf16_t* vrow = vT + ((long)win * 128 + h * 32) * VSTR;
#pragma unroll
    for (int kk = 0; kk < 2; ++kk) {
        bf16x8 vf[2];
#pragma unroll
        for (int dt = 0; dt < 2; ++dt)
            vf[dt] = *reinterpret_cast<const bf16x8*>(
                vrow + (long)(dt * 16 + la) * VSTR + kk * 32 + lb * 8);
        int tl = kk * 2;
#pragma unroll
        for (int qt = 0; qt < 4; ++qt) {
            unsigned int a0 = __shfl(w_[qt][tl][0],     srcA);
            unsigned int b0 = __shfl(w_[qt][tl + 1][0], srcA);
            unsigned int a1 = __shfl(w_[qt][tl][1],     srcA);
            unsigned int b1 = __shfl(w_[qt][tl + 1][1], srcA);
            unsigned int a2 = __shfl(w_[qt][tl][0],     srcB);
            unsigned int b2 = __shfl(w_[qt][tl + 1][0], srcB);
            unsigned int a3 = __shfl(w_[qt][tl][1],     srcB);
            unsigned int b3 = __shfl(w_[qt][tl + 1][1], srcB);
            u32x4 uu = { hiT ? b0 : a0, hiT ? b1 : a1, hiT ? b2 : a2, hiT ? b3 : a3 };
            bf16x8 pf = __builtin_bit_cast(bf16x8, uu);
#pragma unroll
            for (int dt = 0; dt < 2; ++dt)
                O[dt][qt] = __builtin_amdgcn_mfma_f32_16x16x32_bf16(vf[dt], pf, O[dt][qt], 0, 0, 0);
        }
    }

    bf16_t* ob = out + (long)win * 49 * C_ + h * 32;
#pragma unroll
    for (int qt = 0; qt < 4; ++qt) {
        int q = qt * 16 + la;
        if (q < 49) {
            float iv = inv[qt];
#pragma unroll
            for (int dt = 0; dt < 2; ++dt) {
                unsigned int s0 = pk2(O[dt][qt][0] * iv, O[dt][qt][1] * iv);
                unsigned int s1 = pk2(O[dt][qt][2] * iv, O[dt][qt][3] * iv);
                uint2 st = {s0, s1};
                *reinterpret_cast<uint2*>(ob + (long)q * C_ + dt * 16 + lb * 4) = st;
            }
        }
    }
}

// ---------------------------------------------------------------------------
// Fused MLP v5 = v3 structure (32 rows/wave, proven) + fast GELU + fully
// unrolled chunk loop (lets the compiler hoist next chunk's weight loads
// above the GELU->shuffle->fc2 tail). No LDS, no barriers.
// ---------------------------------------------------------------------------
__global__ __launch_bounds__(256) void mlp_fused(const float* __restrict__ y,
                                                 const float* __restrict__ g,
                                                 const float* __restrict__ b,
                                                 const bf16_t* __restrict__ w1t,
                                                 const float* __restrict__ b1,
                                                 const bf16_t* __restrict__ w2t,
                                                 const float* __restrict__ b2,
                                                 float* __restrict__ out)
{
    int lane = threadIdx.x & 63;
    int la = lane & 15, lb = lane >> 4;
    int m0 = (blockIdx.x * 4 + (threadIdx.x >> 6)) * 32;

    // ---- LN2 -> fragments for 2 row-subtiles (m = s*16+la, k = kt*32+lb*8+j)
    bf16x8 af[2][4];
#pragma unroll
    for (int s = 0; s < 2; ++s) {
        const float* yr = y + (long)(m0 + s * 16 + la) * C_;
        float vals[4][8];
        float sm = 0.f, qs = 0.f;
#pragma unroll
        for (int kt = 0; kt < 4; ++kt) {
            f32x4 u0 = *reinterpret_cast<const f32x4*>(yr + kt * 32 + lb * 8);
            f32x4 u1 = *reinterpret_cast<const f32x4*>(yr + kt * 32 + lb * 8 + 4);
#pragma unroll
            for (int j = 0; j < 4; ++j) { vals[kt][j] = u0[j]; vals[kt][4 + j] = u1[j]; }
#pragma unroll
            for (int j = 0; j < 8; ++j) { sm += vals[kt][j]; qs += vals[kt][j] * vals[kt][j]; }
        }
        sm += __shfl_xor(sm, 16); sm += __shfl_xor(sm, 32);
        qs += __shfl_xor(qs, 16); qs += __shfl_xor(qs, 32);
        float mean = sm * (1.f / 128.f);
        float rstd = rsqrtf(qs * (1.f / 128.f) - mean * mean + 1e-5f);
#pragma unroll
        for (int kt = 0; kt < 4; ++kt)
#pragma unroll
            for (int j = 0; j < 8; ++j) {
                int col = kt * 32 + lb * 8 + j;
                af[s][kt][j] = (__bf16)((vals[kt][j] - mean) * rstd * g[col] + b[col]);
            }
    }

    // ---- out^T accumulators: acc[s][nt2]: out[m=s*16+la][n2=nt2*16+lb*4+r]
    f32x4 acc[2][8];
#pragma unroll
    for (int nt2 = 0; nt2 < 8; ++nt2) {
        f32x4 bv = *reinterpret_cast<const f32x4*>(b2 + nt2 * 16 + lb * 4);
#pragma unroll
        for (int s = 0; s < 2; ++s) acc[s][nt2] = bv;
    }

    int srcA = la + (((2 * lb)     & 3) << 4);
    int srcB = la + (((2 * lb + 1) & 3) << 4);
    bool hiT = (lb >> 1) & 1;

#pragma unroll
    for (int c = 0; c < 8; ++c) {
        // ---- fc1 chunk TRANSPOSED: hT[n1][m], n1 = c*64+nt*16+lb*4+r, m = s*16+la
        f32x4 hacc[2][4];
#pragma unroll
        for (int nt = 0; nt < 4; ++nt) {
            f32x4 bv = *reinterpret_cast<const f32x4*>(b1 + c * 64 + nt * 16 + lb * 4);
#pragma unroll
            for (int s = 0; s < 2; ++s) hacc[s][nt] = bv;
        }
#pragma unroll
        for (int kt = 0; kt < 4; ++kt)
#pragma unroll
            for (int nt = 0; nt < 4; ++nt) {
                bf16x8 w1f = *reinterpret_cast<const bf16x8*>(
                    w1t + (long)(c * 64 + nt * 16 + la) * 128 + kt * 32 + lb * 8);
#pragma unroll
                for (int s = 0; s < 2; ++s)
                    hacc[s][nt] = __builtin_amdgcn_mfma_f32_16x16x32_bf16(
                        w1f, af[s][kt], hacc[s][nt], 0, 0, 0);
            }
        // ---- fast GELU + pack to bf16 pairs (hidden pairs along r) ----
        unsigned int wpk[2][4][2];
#pragma unroll
        for (int s = 0; s < 2; ++s)
#pragma unroll
            for (int t = 0; t < 4; ++t) {
                f32x4 hv = hacc[s][t];
#pragma unroll
                for (int r = 0; r < 4; ++r) hv[r] = gelu_f(hv[r]);
                wpk[s][t][0] = pk2(hv[0], hv[1]);
                wpk[s][t][1] = pk2(hv[2], hv[3]);
            }
        // ---- fc2 chunk: acc[s][nt2] += mfma(W2t rows, hT B-frag) ----
#pragma unroll
        for (int kk = 0; kk < 2; ++kk) {
            bf16x8 w2f[8];
#pragma unroll
            for (int nt2 = 0; nt2 < 8; ++nt2)
                w2f[nt2] = *reinterpret_cast<const bf16x8*>(
                    w2t + (long)(nt2 * 16 + la) * 512 + c * 64 + kk * 32 + lb * 8);
            int tl = kk * 2;
#pragma unroll
            for (int s = 0; s < 2; ++s) {
                unsigned int a0 = __shfl(wpk[s][tl][0],     srcA);
                unsigned int b0 = __shfl(wpk[s][tl + 1][0], srcA);
                unsigned int a1 = __shfl(wpk[s][tl][1],     srcA);
                unsigned int b1v = __shfl(wpk[s][tl + 1][1], srcA);
                unsigned int a2 = __shfl(wpk[s][tl][0],     srcB);
                unsigned int b2v = __shfl(wpk[s][tl + 1][0], srcB);
                unsigned int a3 = __shfl(wpk[s][tl][1],     srcB);
                unsigned int b3v = __shfl(wpk[s][tl + 1][1], srcB);
                u32x4 uu = { hiT ? b0 : a0, hiT ? b1v : a1, hiT ? b2v : a2, hiT ? b3v : a3 };
                bf16x8 pf = __builtin_bit_cast(bf16x8, uu);
#pragma unroll
                for (int nt2 = 0; nt2 < 8; ++nt2)
                    acc[s][nt2] = __builtin_amdgcn_mfma_f32_16x16x32_bf16(
                        w2f[nt2], pf, acc[s][nt2], 0, 0, 0);
            }
        }
    }

    // ---- epilogue: + y residual -> out (in-place safe: exclusive rows) ----
#pragma unroll
    for (int s = 0; s < 2; ++s) {
        long m = m0 + s * 16 + la;
        const float* yrow = y + m * C_;
        float* orow = out + m * C_;
#pragma unroll
        for (int nt2 = 0; nt2 < 8; ++nt2) {
            int n2 = nt2 * 16 + lb * 4;
            f32x4 res = *reinterpret_cast<const f32x4*>(yrow + n2);
            f32x4 val = acc[s][nt2] + res;
            *reinterpret_cast<f32x4*>(orow + n2) = val;
        }
    }
}

// ---------------------------------------------------------------------------
extern "C" void kernel_launch(void* const* d_in, const int* in_sizes, int n_in,
                              void* d_out, int out_size, void* d_ws, size_t ws_size,
                              hipStream_t stream)
{
    (void)in_sizes; (void)n_in; (void)out_size;

    const float* x      = (const float*)d_in[0];
    const float* n1g    = (const float*)d_in[1];
    const float* n1b    = (const float*)d_in[2];
    const float* qkv_w  = (const float*)d_in[3];
    const float* qkv_b  = (const float*)d_in[4];
    const float* proj_w = (const float*)d_in[5];
    const float* proj_b = (const float*)d_in[6];
    const float* rpb    = (const float*)d_in[7];
    const float* n2g    = (const float*)d_in[8];
    const float* n2b    = (const float*)d_in[9];
    const float* fc1_w  = (const float*)d_in[10];
    const float* fc1_b  = (const float*)d_in[11];
    const float* fc2_w  = (const float*)d_in[12];
    const float* fc2_b  = (const float*)d_in[13];

    char* ws = (char*)d_ws;

    const size_t qk_sz = (size_t)M_ * 256 * 2;               // 102,760,448
    const size_t vt_sz = (size_t)NWIN * 128 * VSTR * 2;      //  58,720,256
    const size_t at_sz = (size_t)M_ * 128 * 2;               //  51,380,224
    const size_t w_off = qk_sz + vt_sz + at_sz;
    const size_t w_sz  = (size_t)(128 * 384 + 128 * 128 + 128 * 512 + 512 * 128) * 2;
    const size_t need  = w_off + w_sz;                       // ~213.6 MB

    if (need > ws_size) {
        sentinel_kernel<<<1, 256, 0, stream>>>((float*)d_out);
        return;
    }

    bf16_t* qkb  = (bf16_t*)ws;
    bf16_t* vT   = (bf16_t*)(ws + qk_sz);
    bf16_t* attb = (bf16_t*)(ws + qk_sz + vt_sz);
    bf16_t* qkv_wt  = (bf16_t*)(ws + w_off);
    bf16_t* proj_wt = qkv_wt + 128 * 384;
    bf16_t* fc1_wt  = proj_wt + 128 * 128;
    bf16_t* fc2_wt  = fc1_wt + 128 * 512;

    float* y = (float*)d_out;

    transpose_w<<<(128 * 384 + 255) / 256, 256, 0, stream>>>(qkv_w, qkv_wt, 128, 384);
    transpose_w<<<(128 * 128 + 255) / 256, 256, 0, stream>>>(proj_w, proj_wt, 128, 128);
    transpose_w<<<(128 * 512 + 255) / 256, 256, 0, stream>>>(fc1_w, fc1_wt, 128, 512);
    transpose_w<<<(512 * 128 + 255) / 256, 256, 0, stream>>>(fc2_w, fc2_wt, 512, 128);

    // zero vT pad keys (NaN safety for PV fragments)
    zpad_kernel<<<(NWIN * 128 * 7 + 255) / 256, 256, 0, stream>>>(vT);
    // LN1 + shift/window gather fused into QKV projection
    gemm2<128, 384, 1, 0><<<dim3(M_ / 256, 6), 256, 0, stream>>>(
        x, n1g, n1b, qkv_wt, qkv_b, qkb, nullptr, vT);
    // MFMA attention
    attn_mfma<<<NWIN, 256, 0, stream>>>(qkb, vT, rpb, attb);
    // proj + window-reverse + x residual -> f32 y (= d_out)
    gemm2<128, 128, 0, 1><<<dim3(M_ / 256, 2), 256, 0, stream>>>(
        attb, nullptr, nullptr, proj_wt, proj_b, y, x, nullptr);
    // fused LN2 + fc1 + GELU + fc2 + residual (in-place on d_out, no LDS)
    mlp_fused<<<M_ / 128, 256, 0, stream>>>(
        y, n2g, n2b, fc1_wt, fc1_b, fc2_wt, fc2_b, y);
}

// Round 11
// 712.221 us; speedup vs baseline: 1.2538x; 1.1167x over previous
//
#include <hip/hip_runtime.h>
#include <hip/hip_bf16.h>
#include <math.h>

typedef __bf16 bf16x8 __attribute__((ext_vector_type(8)));
typedef float  f32x4  __attribute__((ext_vector_type(4)));
typedef unsigned int u32x4 __attribute__((ext_vector_type(4)));
typedef __hip_bfloat16 bf16_t;

static constexpr int C_    = 128;
static constexpr int L_    = 56 * 56;        // tokens per image
static constexpr int M_    = 64 * L_;        // 200704 total tokens
static constexpr int NWIN  = 64 * 64;        // 4096 windows
static constexpr int VSTR  = 56;             // vT padded key stride

// map windowed token index tw -> unwindowed token index (shift+window bijection)
__device__ inline long win_to_tok(int tw)
{
    int win = tw / 49, n = tw % 49;
    int bb  = win >> 6, wi = win & 63;
    int wh  = wi >> 3, wwp = wi & 7;
    int hs  = wh * 7 + n / 7;
    int wsv = wwp * 7 + n % 7;
    int hh  = (hs + 3) % 56;          // un-shift
    int ww  = (wsv + 3) % 56;
    return (long)bb * L_ + hh * 56 + ww;
}

__device__ inline unsigned int pk2(float lo, float hi)
{
    unsigned short a = __builtin_bit_cast(unsigned short, (__bf16)lo);
    unsigned short b = __builtin_bit_cast(unsigned short, (__bf16)hi);
    return (unsigned int)a | ((unsigned int)b << 16);
}

// tanh-form GELU: ~8 VALU ops, |err| <= ~3e-3 (threshold is 0.11).
__device__ inline float gelu_f(float x)
{
    float u = 0.7978845608f * x * (1.f + 0.044715f * x * x);
    float e = __expf(2.f * fminf(u, 15.f));
    return x * e * __builtin_amdgcn_rcpf(e + 1.f);
}

__global__ void sentinel_kernel(float* o) { o[threadIdx.x] = 1e9f; }

// ---------------------------------------------------------------------------
__global__ void transpose_w(const float* __restrict__ w, bf16_t* __restrict__ wt,
                            int K, int N)
{
    int i = blockIdx.x * 256 + threadIdx.x;
    if (i >= K * N) return;
    int k = i / N, n = i % N;
    wt[(long)n * K + k] = __float2bfloat16(w[i]);
}

// zero vT pad keys 49..55 for all (win, d)
__global__ void zpad_kernel(bf16_t* __restrict__ vT)
{
    long i = (long)blockIdx.x * 256 + threadIdx.x;
    if (i >= (long)NWIN * 128 * 7) return;
    long row = i / 7;
    int  k   = 49 + (int)(i % 7);
    vT[row * VSTR + k] = __float2bfloat16(0.f);
}

// ---------------------------------------------------------------------------
// GEMM, one wave = 64x64 output tile. Block = 4 waves stacked in M (256 rows).
// grid = (M/256, N/64).
// LNM: 0 = A is plain bf16 row-major
//      1 = A = LN1(gather shifted/windowed row of x f32)   [qkv]
// EPI: 0 = qkv: cols<256 -> qk[token][256]; cols>=256 -> vT[win][d][key]
//      1 = proj: window-reverse + unshift + x(f32) residual -> f32 out
// ---------------------------------------------------------------------------
template<int K, int N, int LNM, int EPI>
__global__ __launch_bounds__(256) void gemm2(const void*  __restrict__ Asrc,
                                             const float* __restrict__ lng,
                                             const float* __restrict__ lnb,
                                             const bf16_t* __restrict__ Bt,
                                             const float*  __restrict__ bias,
                                             void*         outp,
                                             const float*  resf,
                                             bf16_t*       vTp)
{
    int lane = threadIdx.x & 63;
    int wave = threadIdx.x >> 6;
    int la = lane & 15, lb = lane >> 4;
    int m0   = (blockIdx.x * 4 + wave) * 64;
    int c0   = blockIdx.y * 64;

    f32x4 acc[4][4];
#pragma unroll
    for (int nt = 0; nt < 4; ++nt) {
        float bv = bias[c0 + nt * 16 + la];
#pragma unroll
        for (int s = 0; s < 4; ++s) acc[s][nt] = (f32x4){bv, bv, bv, bv};
    }

    static_assert(K == 128, "gemm2 is K=128 only now");
    bf16x8 areg[4][4];
    if constexpr (LNM == 0) {
#pragma unroll
        for (int s = 0; s < 4; ++s)
#pragma unroll
            for (int kt = 0; kt < 4; ++kt)
                areg[s][kt] = *reinterpret_cast<const bf16x8*>(
                    (const bf16_t*)Asrc + (long)(m0 + s * 16 + la) * K + kt * 32 + lb * 8);
    } else {
#pragma unroll
        for (int s = 0; s < 4; ++s) {
            long src = win_to_tok(m0 + s * 16 + la);
            const float* xr = (const float*)Asrc + src * C_;
            float vals[4][8];
            float sm = 0.f, qs = 0.f;
#pragma unroll
            for (int kt = 0; kt < 4; ++kt) {
                f32x4 u0 = *reinterpret_cast<const f32x4*>(xr + kt * 32 + lb * 8);
                f32x4 u1 = *reinterpret_cast<const f32x4*>(xr + kt * 32 + lb * 8 + 4);
#pragma unroll
                for (int j = 0; j < 4; ++j) { vals[kt][j] = u0[j]; vals[kt][4 + j] = u1[j]; }
#pragma unroll
                for (int j = 0; j < 8; ++j) { sm += vals[kt][j]; qs += vals[kt][j] * vals[kt][j]; }
            }
            sm += __shfl_xor(sm, 16); sm += __shfl_xor(sm, 32);
            qs += __shfl_xor(qs, 16); qs += __shfl_xor(qs, 32);
            float mean = sm * (1.f / 128.f);
            float rstd = rsqrtf(qs * (1.f / 128.f) - mean * mean + 1e-5f);
#pragma unroll
            for (int kt = 0; kt < 4; ++kt)
#pragma unroll
                for (int j = 0; j < 8; ++j) {
                    int col = kt * 32 + lb * 8 + j;
                    areg[s][kt][j] = (__bf16)((vals[kt][j] - mean) * rstd * lng[col] + lnb[col]);
                }
        }
    }

    bf16x8 breg[4][4];
#pragma unroll
    for (int kt = 0; kt < 4; ++kt)
#pragma unroll
        for (int nt = 0; nt < 4; ++nt)
            breg[kt][nt] = *reinterpret_cast<const bf16x8*>(
                Bt + (long)(c0 + nt * 16 + la) * K + kt * 32 + lb * 8);
#pragma unroll
    for (int kt = 0; kt < 4; ++kt)
#pragma unroll
        for (int nt = 0; nt < 4; ++nt)
#pragma unroll
            for (int s = 0; s < 4; ++s)
                acc[s][nt] = __builtin_amdgcn_mfma_f32_16x16x32_bf16(
                    areg[s][kt], breg[kt][nt], acc[s][nt], 0, 0, 0);

#pragma unroll
    for (int s = 0; s < 4; ++s) {
#pragma unroll
        for (int r = 0; r < 4; ++r) {
            int row = m0 + s * 16 + lb * 4 + r;
            if constexpr (EPI == 0) {
                int win = row / 49, key = row - win * 49;
#pragma unroll
                for (int nt = 0; nt < 4; ++nt) {
                    int col = c0 + nt * 16 + la;
                    float v = acc[s][nt][r];
                    if (col < 256)
                        ((bf16_t*)outp)[(long)row * 256 + col] = __float2bfloat16(v);
                    else
                        vTp[((long)win * 128 + (col - 256)) * VSTR + key] = __float2bfloat16(v);
                }
            } else {
                long to = win_to_tok(row);
#pragma unroll
                for (int nt = 0; nt < 4; ++nt) {
                    int col = c0 + nt * 16 + la;
                    ((float*)outp)[to * C_ + col] = acc[s][nt][r] + resf[to * C_ + col];
                }
            }
        }
    }
}

// ---------------------------------------------------------------------------
// MFMA windowed attention: one block per window, one wave per head. No LDS.
// ---------------------------------------------------------------------------
__global__ __launch_bounds__(256) void attn_mfma(const bf16_t* __restrict__ qk,
                                                 const bf16_t* __restrict__ vT,
                                                 const float*  __restrict__ rpb,
                                                 bf16_t* __restrict__ out)
{
    int win  = blockIdx.x;
    int h    = threadIdx.x >> 6;
    int lane = threadIdx.x & 63;
    int la = lane & 15, lb = lane >> 4;

    const bf16_t* qkw = qk + (long)win * 49 * 256;

    bf16x8 kf[4], qf[4];
#pragma unroll
    for (int t = 0; t < 4; ++t) {
        kf[t] = *reinterpret_cast<const bf16x8*>(qkw + (long)(t * 16 + la) * 256 + 128 + h * 32 + lb * 8);
        qf[t] = *reinterpret_cast<const bf16x8*>(qkw + (long)(t * 16 + la) * 256 +       h * 32 + lb * 8);
    }

    f32x4 S[4][4];
#pragma unroll
    for (int qt = 0; qt < 4; ++qt)
#pragma unroll
        for (int kt = 0; kt < 4; ++kt)
            S[qt][kt] = __builtin_amdgcn_mfma_f32_16x16x32_bf16(
                kf[kt], qf[qt], (f32x4){0.f, 0.f, 0.f, 0.f}, 0, 0, 0);

    const float scale = 0.17677669529663687f;   // 1/sqrt(32)
    int wi  = win & 63;
    int wh  = wi >> 3, wwp = wi & 7;
    bool edge = (wh == 7) || (wwp == 7);

    int i1[4], j1[4], r1[4], c1[4];
#pragma unroll
    for (int qt = 0; qt < 4; ++qt) {
        int q  = qt * 16 + la;
        int qc = q < 49 ? q : 48;
        i1[qt] = qc / 7; j1[qt] = qc - 7 * i1[qt];
        r1[qt] = (wh  < 7) ? 0 : ((i1[qt] < 4) ? 1 : 2);
        c1[qt] = (wwp < 7) ? 0 : ((j1[qt] < 4) ? 1 : 2);
    }

#pragma unroll
    for (int kt = 0; kt < 4; ++kt) {
#pragma unroll
        for (int r = 0; r < 4; ++r) {
            if (kt == 3 && r > 0) {
#pragma unroll
                for (int qt = 0; qt < 4; ++qt) S[qt][kt][r] = -1e30f;
                continue;
            }
            int key = kt * 16 + lb * 4 + r;
            int kc  = key < 49 ? key : 48;
            int i2  = kc / 7, j2 = kc - 7 * i2;
            int r2  = (wh  < 7) ? 0 : ((i2 < 4) ? 1 : 2);
            int c2  = (wwp < 7) ? 0 : ((j2 < 4) ? 1 : 2);
#pragma unroll
            for (int qt = 0; qt < 4; ++qt) {
                float bv  = rpb[(((i1[qt] - i2 + 6) * 13 + (j1[qt] - j2 + 6)) << 2) + h];
                float val = S[qt][kt][r] * scale + bv;
                if (edge && ((r1[qt] != r2) | (c1[qt] != c2))) val -= 100.f;
                if (kt == 3 && lb > 0) val = -1e30f;
                S[qt][kt][r] = val;
            }
        }
    }

    float inv[4];
#pragma unroll
    for (int qt = 0; qt < 4; ++qt) {
        float mx = -3e38f;
#pragma unroll
        for (int kt = 0; kt < 4; ++kt)
#pragma unroll
            for (int r = 0; r < 4; ++r) mx = fmaxf(mx, S[qt][kt][r]);
        mx = fmaxf(mx, __shfl_xor(mx, 16));
        mx = fmaxf(mx, __shfl_xor(mx, 32));
        float sm = 0.f;
#pragma unroll
        for (int kt = 0; kt < 4; ++kt)
#pragma unroll
            for (int r = 0; r < 4; ++r) {
                float e = __expf(S[qt][kt][r] - mx);
                S[qt][kt][r] = e;
                sm += e;
            }
        sm += __shfl_xor(sm, 16);
        sm += __shfl_xor(sm, 32);
        inv[qt] = 1.f / sm;
    }

    unsigned int w_[4][4][2];
#pragma unroll
    for (int qt = 0; qt < 4; ++qt)
#pragma unroll
        for (int t = 0; t < 4; ++t) {
            w_[qt][t][0] = pk2(S[qt][t][0], S[qt][t][1]);
            w_[qt][t][1] = pk2(S[qt][t][2], S[qt][t][3]);
        }

    int srcA = la + (((2 * lb)     & 3) << 4);
    int srcB = la + (((2 * lb + 1) & 3) << 4);
    bool hiT = (lb >> 1) & 1;

    f32x4 O[2][4];
#pragma unroll
    for (int dt = 0; dt < 2; ++dt)
#pragma unroll
        for (int qt = 0; qt < 4; ++qt) O[dt][qt] = (f32x4){0.f, 0.f, 0.f, 0.f};

    const bf16_t* vrow = vT + ((long)win * 128 + h * 32) * VSTR;
#pragma unroll
    for (int kk = 0; kk < 2; ++kk) {
        bf16x8 vf[2];
#pragma unroll
        for (int dt = 0; dt < 2; ++dt)
            vf[dt] = *reinterpret_cast<const bf16x8*>(
                vrow + (long)(dt * 16 + la) * VSTR + kk * 32 + lb * 8);
        int tl = kk * 2;
#pragma unroll
        for (int qt = 0; qt < 4; ++qt) {
            unsigned int a0 = __shfl(w_[qt][tl][0],     srcA);
            unsigned int b0 = __shfl(w_[qt][tl + 1][0], srcA);
            unsigned int a1 = __shfl(w_[qt][tl][1],     srcA);
            unsigned int b1 = __shfl(w_[qt][tl + 1][1], srcA);
            unsigned int a2 = __shfl(w_[qt][tl][0],     srcB);
            unsigned int b2 = __shfl(w_[qt][tl + 1][0], srcB);
            unsigned int a3 = __shfl(w_[qt][tl][1],     srcB);
            unsigned int b3 = __shfl(w_[qt][tl + 1][1], srcB);
            u32x4 uu = { hiT ? b0 : a0, hiT ? b1 : a1, hiT ? b2 : a2, hiT ? b3 : a3 };
            bf16x8 pf = __builtin_bit_cast(bf16x8, uu);
#pragma unroll
            for (int dt = 0; dt < 2; ++dt)
                O[dt][qt] = __builtin_amdgcn_mfma_f32_16x16x32_bf16(vf[dt], pf, O[dt][qt], 0, 0, 0);
        }
    }

    bf16_t* ob = out + (long)win * 49 * C_ + h * 32;
#pragma unroll
    for (int qt = 0; qt < 4; ++qt) {
        int q = qt * 16 + la;
        if (q < 49) {
            float iv = inv[qt];
#pragma unroll
            for (int dt = 0; dt < 2; ++dt) {
                unsigned int s0 = pk2(O[dt][qt][0] * iv, O[dt][qt][1] * iv);
                unsigned int s1 = pk2(O[dt][qt][2] * iv, O[dt][qt][3] * iv);
                uint2 st = {s0, s1};
                *reinterpret_cast<uint2*>(ob + (long)q * C_ + dt * 16 + lb * 4) = st;
            }
        }
    }
}

// ---------------------------------------------------------------------------
// Fused MLP v6 = v3 structure (32 rows/wave) + cooperative double-buffered
// LDS weight staging. Per chunk c: block stages W1-slice (64x128) + W2-slice
// (128x64) into LDS (XOR-swizzled rows, ((row&7)<<4) on byte offset) while
// computing chunk c from the other buffer. One barrier per chunk.
// fc1 TRANSPOSED (hT in attention-repack source layout); verified shuffle
// builds fc2 B-fragments; out^T acc, f32x4 stores.
// ---------------------------------------------------------------------------
__global__ __launch_bounds__(256) void mlp_fused(const float* __restrict__ y,
                                                 const float* __restrict__ g,
                                                 const float* __restrict__ b,
                                                 const bf16_t* __restrict__ w1t,
                                                 const float* __restrict__ b1,
                                                 const bf16_t* __restrict__ w2t,
                                                 const float* __restrict__ b2,
                                                 float* __restrict__ out)
{
    __shared__ uint4 ldsq[2][2048];          // 2 x 32 KB: [W1c 16KB | W2c 16KB]
    int tid  = threadIdx.x;
    int lane = tid & 63;
    int la = lane & 15, lb = lane >> 4;
    int m0 = (blockIdx.x * 4 + (tid >> 6)) * 32;

    // cooperative stage of chunk c into buffer p
    auto stage = [&](int c, int p) {
        char* d1 = (char*)&ldsq[p][0];
        const char* s1 = (const char*)w1t + (size_t)c * 16384;
#pragma unroll
        for (int i = 0; i < 4; ++i) {
            int idx = i * 256 + tid;               // 0..1023, 16B units
            int row = idx >> 4, colb = (idx & 15) * 16;
            uint4 v = *reinterpret_cast<const uint4*>(s1 + idx * 16);
            *reinterpret_cast<uint4*>(d1 + row * 256 + (colb ^ ((row & 7) << 4))) = v;
        }
        char* d2 = (char*)&ldsq[p][1024];
        const char* s2 = (const char*)w2t + (size_t)c * 128;
#pragma unroll
        for (int i = 0; i < 4; ++i) {
            int idx = i * 256 + tid;               // 0..1023
            int row = idx >> 3, colb = (idx & 7) * 16;
            uint4 v = *reinterpret_cast<const uint4*>(s2 + (size_t)row * 1024 + colb);
            *reinterpret_cast<uint4*>(d2 + row * 128 + (colb ^ ((row & 7) << 4))) = v;
        }
    };

    // ---- LN2 -> fragments for 2 row-subtiles (m = s*16+la, k = kt*32+lb*8+j)
    bf16x8 af[2][4];
#pragma unroll
    for (int s = 0; s < 2; ++s) {
        const float* yr = y + (long)(m0 + s * 16 + la) * C_;
        float vals[4][8];
        float sm = 0.f, qs = 0.f;
#pragma unroll
        for (int kt = 0; kt < 4; ++kt) {
            f32x4 u0 = *reinterpret_cast<const f32x4*>(yr + kt * 32 + lb * 8);
            f32x4 u1 = *reinterpret_cast<const f32x4*>(yr + kt * 32 + lb * 8 + 4);
#pragma unroll
            for (int j = 0; j < 4; ++j) { vals[kt][j] = u0[j]; vals[kt][4 + j] = u1[j]; }
#pragma unroll
            for (int j = 0; j < 8; ++j) { sm += vals[kt][j]; qs += vals[kt][j] * vals[kt][j]; }
        }
        sm += __shfl_xor(sm, 16); sm += __shfl_xor(sm, 32);
        qs += __shfl_xor(qs, 16); qs += __shfl_xor(qs, 32);
        float mean = sm * (1.f / 128.f);
        float rstd = rsqrtf(qs * (1.f / 128.f) - mean * mean + 1e-5f);
#pragma unroll
        for (int kt = 0; kt < 4; ++kt)
#pragma unroll
            for (int j = 0; j < 8; ++j) {
                int col = kt * 32 + lb * 8 + j;
                af[s][kt][j] = (__bf16)((vals[kt][j] - mean) * rstd * g[col] + b[col]);
            }
    }

    // ---- out^T accumulators: acc[s][nt2]: out[m=s*16+la][n2=nt2*16+lb*4+r]
    f32x4 acc[2][8];
#pragma unroll
    for (int nt2 = 0; nt2 < 8; ++nt2) {
        f32x4 bv = *reinterpret_cast<const f32x4*>(b2 + nt2 * 16 + lb * 4);
#pragma unroll
        for (int s = 0; s < 2; ++s) acc[s][nt2] = bv;
    }

    int srcA = la + (((2 * lb)     & 3) << 4);
    int srcB = la + (((2 * lb + 1) & 3) << 4);
    bool hiT = (lb >> 1) & 1;

    stage(0, 0);
    __syncthreads();

    for (int c = 0; c < 8; ++c) {
        int p = c & 1;
        if (c < 7) stage(c + 1, p ^ 1);      // issue-early: hides under compute

        const char* L1 = (const char*)&ldsq[p][0];
        const char* L2 = (const char*)&ldsq[p][1024];

        // ---- fc1 chunk TRANSPOSED from LDS: hT[n1][m] ----
        f32x4 hacc[2][4];
#pragma unroll
        for (int nt = 0; nt < 4; ++nt) {
            f32x4 bv = *reinterpret_cast<const f32x4*>(b1 + c * 64 + nt * 16 + lb * 4);
#pragma unroll
            for (int s = 0; s < 2; ++s) hacc[s][nt] = bv;
        }
#pragma unroll
        for (int kt = 0; kt < 4; ++kt)
#pragma unroll
            for (int nt = 0; nt < 4; ++nt) {
                int row = nt * 16 + la;
                bf16x8 w1f = *reinterpret_cast<const bf16x8*>(
                    L1 + row * 256 + ((kt * 64 + lb * 16) ^ ((row & 7) << 4)));
#pragma unroll
                for (int s = 0; s < 2; ++s)
                    hacc[s][nt] = __builtin_amdgcn_mfma_f32_16x16x32_bf16(
                        w1f, af[s][kt], hacc[s][nt], 0, 0, 0);
            }
        // ---- fast GELU + pack to bf16 pairs ----
        unsigned int wpk[2][4][2];
#pragma unroll
        for (int s = 0; s < 2; ++s)
#pragma unroll
            for (int t = 0; t < 4; ++t) {
                f32x4 hv = hacc[s][t];
#pragma unroll
                for (int r = 0; r < 4; ++r) hv[r] = gelu_f(hv[r]);
                wpk[s][t][0] = pk2(hv[0], hv[1]);
                wpk[s][t][1] = pk2(hv[2], hv[3]);
            }
        // ---- fc2 chunk: acc[s][nt2] += mfma(W2 rows from LDS, hT B-frag) ----
#pragma unroll
        for (int kk = 0; kk < 2; ++kk) {
            int tl = kk * 2;
#pragma unroll
            for (int s = 0; s < 2; ++s) {
                unsigned int a0 = __shfl(wpk[s][tl][0],     srcA);
                unsigned int b0 = __shfl(wpk[s][tl + 1][0], srcA);
                unsigned int a1 = __shfl(wpk[s][tl][1],     srcA);
                unsigned int b1v = __shfl(wpk[s][tl + 1][1], srcA);
                unsigned int a2 = __shfl(wpk[s][tl][0],     srcB);
                unsigned int b2v = __shfl(wpk[s][tl + 1][0], srcB);
                unsigned int a3 = __shfl(wpk[s][tl][1],     srcB);
                unsigned int b3v = __shfl(wpk[s][tl + 1][1], srcB);
                u32x4 uu = { hiT ? b0 : a0, hiT ? b1v : a1, hiT ? b2v : a2, hiT ? b3v : a3 };
                bf16x8 pf = __builtin_bit_cast(bf16x8, uu);
#pragma unroll
                for (int nt2 = 0; nt2 < 8; ++nt2) {
                    int row2 = nt2 * 16 + la;
                    bf16x8 w2f = *reinterpret_cast<const bf16x8*>(
                        L2 + row2 * 128 + ((kk * 64 + lb * 16) ^ ((row2 & 7) << 4)));
                    acc[s][nt2] = __builtin_amdgcn_mfma_f32_16x16x32_bf16(
                        w2f, pf, acc[s][nt2], 0, 0, 0);
                }
            }
        }
        __syncthreads();   // stage(c+1) complete; buf p free for stage(c+2)
    }

    // ---- epilogue: + y residual -> out (in-place safe: exclusive rows) ----
#pragma unroll
    for (int s = 0; s < 2; ++s) {
        long m = m0 + s * 16 + la;
        const float* yrow = y + m * C_;
        float* orow = out + m * C_;
#pragma unroll
        for (int nt2 = 0; nt2 < 8; ++nt2) {
            int n2 = nt2 * 16 + lb * 4;
            f32x4 res = *reinterpret_cast<const f32x4*>(yrow + n2);
            f32x4 val = acc[s][nt2] + res;
            *reinterpret_cast<f32x4*>(orow + n2) = val;
        }
    }
}

// ---------------------------------------------------------------------------
extern "C" void kernel_launch(void* const* d_in, const int* in_sizes, int n_in,
                              void* d_out, int out_size, void* d_ws, size_t ws_size,
                              hipStream_t stream)
{
    (void)in_sizes; (void)n_in; (void)out_size;

    const float* x      = (const float*)d_in[0];
    const float* n1g    = (const float*)d_in[1];
    const float* n1b    = (const float*)d_in[2];
    const float* qkv_w  = (const float*)d_in[3];
    const float* qkv_b  = (const float*)d_in[4];
    const float* proj_w = (const float*)d_in[5];
    const float* proj_b = (const float*)d_in[6];
    const float* rpb    = (const float*)d_in[7];
    const float* n2g    = (const float*)d_in[8];
    const float* n2b    = (const float*)d_in[9];
    const float* fc1_w  = (const float*)d_in[10];
    const float* fc1_b  = (const float*)d_in[11];
    const float* fc2_w  = (const float*)d_in[12];
    const float* fc2_b  = (const float*)d_in[13];

    char* ws = (char*)d_ws;

    const size_t qk_sz = (size_t)M_ * 256 * 2;               // 102,760,448
    const size_t vt_sz = (size_t)NWIN * 128 * VSTR * 2;      //  58,720,256
    const size_t at_sz = (size_t)M_ * 128 * 2;               //  51,380,224
    const size_t w_off = qk_sz + vt_sz + at_sz;
    const size_t w_sz  = (size_t)(128 * 384 + 128 * 128 + 128 * 512 + 512 * 128) * 2;
    const size_t need  = w_off + w_sz;                       // ~213.6 MB

    if (need > ws_size) {
        sentinel_kernel<<<1, 256, 0, stream>>>((float*)d_out);
        return;
    }

    bf16_t* qkb  = (bf16_t*)ws;
    bf16_t* vT   = (bf16_t*)(ws + qk_sz);
    bf16_t* attb = (bf16_t*)(ws + qk_sz + vt_sz);
    bf16_t* qkv_wt  = (bf16_t*)(ws + w_off);
    bf16_t* proj_wt = qkv_wt + 128 * 384;
    bf16_t* fc1_wt  = proj_wt + 128 * 128;
    bf16_t* fc2_wt  = fc1_wt + 128 * 512;

    float* y = (float*)d_out;

    transpose_w<<<(128 * 384 + 255) / 256, 256, 0, stream>>>(qkv_w, qkv_wt, 128, 384);
    transpose_w<<<(128 * 128 + 255) / 256, 256, 0, stream>>>(proj_w, proj_wt, 128, 128);
    transpose_w<<<(128 * 512 + 255) / 256, 256, 0, stream>>>(fc1_w, fc1_wt, 128, 512);
    transpose_w<<<(512 * 128 + 255) / 256, 256, 0, stream>>>(fc2_w, fc2_wt, 512, 128);

    // zero vT pad keys (NaN safety for PV fragments)
    zpad_kernel<<<(NWIN * 128 * 7 + 255) / 256, 256, 0, stream>>>(vT);
    // LN1 + shift/window gather fused into QKV projection
    gemm2<128, 384, 1, 0><<<dim3(M_ / 256, 6), 256, 0, stream>>>(
        x, n1g, n1b, qkv_wt, qkv_b, qkb, nullptr, vT);
    // MFMA attention
    attn_mfma<<<NWIN, 256, 0, stream>>>(qkb, vT, rpb, attb);
    // proj + window-reverse + x residual -> f32 y (= d_out)
    gemm2<128, 128, 0, 1><<<dim3(M_ / 256, 2), 256, 0, stream>>>(
        attb, nullptr, nullptr, proj_wt, proj_b, y, x, nullptr);
    // fused LN2 + fc1 + GELU + fc2 + residual (LDS-staged weights)
    mlp_fused<<<M_ / 128, 256, 0, stream>>>(
        y, n2g, n2b, fc1_wt, fc1_b, fc2_wt, fc2_b, y);
}

// Round 12
// 595.409 us; speedup vs baseline: 1.4998x; 1.1962x over previous
//
#include <hip/hip_runtime.h>
#include <hip/hip_bf16.h>
#include <math.h>

typedef __bf16 bf16x8 __attribute__((ext_vector_type(8)));
typedef float  f32x4  __attribute__((ext_vector_type(4)));
typedef unsigned int u32x4 __attribute__((ext_vector_type(4)));
typedef __hip_bfloat16 bf16_t;

static constexpr int C_    = 128;
static constexpr int L_    = 56 * 56;        // tokens per image
static constexpr int M_    = 64 * L_;        // 200704 total tokens
static constexpr int NWIN  = 64 * 64;        // 4096 windows
static constexpr int VSTR  = 56;             // vT padded key stride

// map windowed token index tw -> unwindowed token index (shift+window bijection)
__device__ inline long win_to_tok(int tw)
{
    int win = tw / 49, n = tw % 49;
    int bb  = win >> 6, wi = win & 63;
    int wh  = wi >> 3, wwp = wi & 7;
    int hs  = wh * 7 + n / 7;
    int wsv = wwp * 7 + n % 7;
    int hh  = (hs + 3) % 56;          // un-shift
    int ww  = (wsv + 3) % 56;
    return (long)bb * L_ + hh * 56 + ww;
}

__device__ inline unsigned int pk2(float lo, float hi)
{
    unsigned short a = __builtin_bit_cast(unsigned short, (__bf16)lo);
    unsigned short b = __builtin_bit_cast(unsigned short, (__bf16)hi);
    return (unsigned int)a | ((unsigned int)b << 16);
}

// tanh-form GELU: ~8 VALU ops, |err| <= ~3e-3 (threshold is 0.11).
__device__ inline float gelu_f(float x)
{
    float u = 0.7978845608f * x * (1.f + 0.044715f * x * x);
    float e = __expf(2.f * fminf(u, 15.f));
    return x * e * __builtin_amdgcn_rcpf(e + 1.f);
}

__global__ void sentinel_kernel(float* o) { o[threadIdx.x] = 1e9f; }

// ---------------------------------------------------------------------------
__global__ void transpose_w(const float* __restrict__ w, bf16_t* __restrict__ wt,
                            int K, int N)
{
    int i = blockIdx.x * 256 + threadIdx.x;
    if (i >= K * N) return;
    int k = i / N, n = i % N;
    wt[(long)n * K + k] = __float2bfloat16(w[i]);
}

// zero vT pad keys 49..55 for all (win, d)
__global__ void zpad_kernel(bf16_t* __restrict__ vT)
{
    long i = (long)blockIdx.x * 256 + threadIdx.x;
    if (i >= (long)NWIN * 128 * 7) return;
    long row = i / 7;
    int  k   = 49 + (int)(i % 7);
    vT[row * VSTR + k] = __float2bfloat16(0.f);
}

// ---------------------------------------------------------------------------
// GEMM, one wave = 64x64 output tile. Block = 4 waves stacked in M (256 rows).
// grid = (M/256, N/64). LNM=1: A = LN1(gather shifted/windowed row of x f32).
// EPI=0 (qkv): cols<256 -> qk[token][256]; cols>=256 -> vT[win][d][key]
// ---------------------------------------------------------------------------
template<int K, int N, int LNM, int EPI>
__global__ __launch_bounds__(256) void gemm2(const void*  __restrict__ Asrc,
                                             const float* __restrict__ lng,
                                             const float* __restrict__ lnb,
                                             const bf16_t* __restrict__ Bt,
                                             const float*  __restrict__ bias,
                                             void*         outp,
                                             const float*  resf,
                                             bf16_t*       vTp)
{
    int lane = threadIdx.x & 63;
    int wave = threadIdx.x >> 6;
    int la = lane & 15, lb = lane >> 4;
    int m0   = (blockIdx.x * 4 + wave) * 64;
    int c0   = blockIdx.y * 64;

    f32x4 acc[4][4];
#pragma unroll
    for (int nt = 0; nt < 4; ++nt) {
        float bv = bias[c0 + nt * 16 + la];
#pragma unroll
        for (int s = 0; s < 4; ++s) acc[s][nt] = (f32x4){bv, bv, bv, bv};
    }

    static_assert(K == 128, "gemm2 is K=128 only now");
    bf16x8 areg[4][4];
    if constexpr (LNM == 0) {
#pragma unroll
        for (int s = 0; s < 4; ++s)
#pragma unroll
            for (int kt = 0; kt < 4; ++kt)
                areg[s][kt] = *reinterpret_cast<const bf16x8*>(
                    (const bf16_t*)Asrc + (long)(m0 + s * 16 + la) * K + kt * 32 + lb * 8);
    } else {
#pragma unroll
        for (int s = 0; s < 4; ++s) {
            long src = win_to_tok(m0 + s * 16 + la);
            const float* xr = (const float*)Asrc + src * C_;
            float vals[4][8];
            float sm = 0.f, qs = 0.f;
#pragma unroll
            for (int kt = 0; kt < 4; ++kt) {
                f32x4 u0 = *reinterpret_cast<const f32x4*>(xr + kt * 32 + lb * 8);
                f32x4 u1 = *reinterpret_cast<const f32x4*>(xr + kt * 32 + lb * 8 + 4);
#pragma unroll
                for (int j = 0; j < 4; ++j) { vals[kt][j] = u0[j]; vals[kt][4 + j] = u1[j]; }
#pragma unroll
                for (int j = 0; j < 8; ++j) { sm += vals[kt][j]; qs += vals[kt][j] * vals[kt][j]; }
            }
            sm += __shfl_xor(sm, 16); sm += __shfl_xor(sm, 32);
            qs += __shfl_xor(qs, 16); qs += __shfl_xor(qs, 32);
            float mean = sm * (1.f / 128.f);
            float rstd = rsqrtf(qs * (1.f / 128.f) - mean * mean + 1e-5f);
#pragma unroll
            for (int kt = 0; kt < 4; ++kt)
#pragma unroll
                for (int j = 0; j < 8; ++j) {
                    int col = kt * 32 + lb * 8 + j;
                    areg[s][kt][j] = (__bf16)((vals[kt][j] - mean) * rstd * lng[col] + lnb[col]);
                }
        }
    }

    bf16x8 breg[4][4];
#pragma unroll
    for (int kt = 0; kt < 4; ++kt)
#pragma unroll
        for (int nt = 0; nt < 4; ++nt)
            breg[kt][nt] = *reinterpret_cast<const bf16x8*>(
                Bt + (long)(c0 + nt * 16 + la) * K + kt * 32 + lb * 8);
#pragma unroll
    for (int kt = 0; kt < 4; ++kt)
#pragma unroll
        for (int nt = 0; nt < 4; ++nt)
#pragma unroll
            for (int s = 0; s < 4; ++s)
                acc[s][nt] = __builtin_amdgcn_mfma_f32_16x16x32_bf16(
                    areg[s][kt], breg[kt][nt], acc[s][nt], 0, 0, 0);

#pragma unroll
    for (int s = 0; s < 4; ++s) {
#pragma unroll
        for (int r = 0; r < 4; ++r) {
            int row = m0 + s * 16 + lb * 4 + r;
            if constexpr (EPI == 0) {
                int win = row / 49, key = row - win * 49;
#pragma unroll
                for (int nt = 0; nt < 4; ++nt) {
                    int col = c0 + nt * 16 + la;
                    float v = acc[s][nt][r];
                    if (col < 256)
                        ((bf16_t*)outp)[(long)row * 256 + col] = __float2bfloat16(v);
                    else
                        vTp[((long)win * 128 + (col - 256)) * VSTR + key] = __float2bfloat16(v);
                }
            } else {
                long to = win_to_tok(row);
#pragma unroll
                for (int nt = 0; nt < 4; ++nt) {
                    int col = c0 + nt * 16 + la;
                    ((float*)outp)[to * C_ + col] = acc[s][nt][r] + resf[to * C_ + col];
                }
            }
        }
    }
}

// ---------------------------------------------------------------------------
// MFMA windowed attention + fused proj + window-reverse + x residual.
// One block per window, one wave per head. After PV, normalized O goes to
// LDS attw[49][152] (152-pad: 304B rows, 16B-aligned, bank-stride 12 mod 32);
// one barrier; each wave then computes a 64x32 proj tile (A from LDS,
// B = proj_wt rows) and writes f32 y with window-reverse + residual.
// Rows q>=49 read uninit LDS but MFMA rows are independent -> never stored.
// ---------------------------------------------------------------------------
__global__ __launch_bounds__(256) void attn_mfma(const bf16_t* __restrict__ qk,
                                                 const bf16_t* __restrict__ vT,
                                                 const float*  __restrict__ rpb,
                                                 const bf16_t* __restrict__ projwt,
                                                 const float*  __restrict__ projb,
                                                 const float*  __restrict__ x,
                                                 float* __restrict__ y)
{
    int win  = blockIdx.x;
    int h    = threadIdx.x >> 6;
    int lane = threadIdx.x & 63;
    int la = lane & 15, lb = lane >> 4;

    __shared__ __bf16 attw[49][152];

    const bf16_t* qkw = qk + (long)win * 49 * 256;

    bf16x8 kf[4], qf[4];
#pragma unroll
    for (int t = 0; t < 4; ++t) {
        kf[t] = *reinterpret_cast<const bf16x8*>(qkw + (long)(t * 16 + la) * 256 + 128 + h * 32 + lb * 8);
        qf[t] = *reinterpret_cast<const bf16x8*>(qkw + (long)(t * 16 + la) * 256 +       h * 32 + lb * 8);
    }

    f32x4 S[4][4];
#pragma unroll
    for (int qt = 0; qt < 4; ++qt)
#pragma unroll
        for (int kt = 0; kt < 4; ++kt)
            S[qt][kt] = __builtin_amdgcn_mfma_f32_16x16x32_bf16(
                kf[kt], qf[qt], (f32x4){0.f, 0.f, 0.f, 0.f}, 0, 0, 0);

    const float scale = 0.17677669529663687f;   // 1/sqrt(32)
    int wi  = win & 63;
    int wh  = wi >> 3, wwp = wi & 7;
    bool edge = (wh == 7) || (wwp == 7);

    int i1[4], j1[4], r1[4], c1[4];
#pragma unroll
    for (int qt = 0; qt < 4; ++qt) {
        int q  = qt * 16 + la;
        int qc = q < 49 ? q : 48;
        i1[qt] = qc / 7; j1[qt] = qc - 7 * i1[qt];
        r1[qt] = (wh  < 7) ? 0 : ((i1[qt] < 4) ? 1 : 2);
        c1[qt] = (wwp < 7) ? 0 : ((j1[qt] < 4) ? 1 : 2);
    }

#pragma unroll
    for (int kt = 0; kt < 4; ++kt) {
#pragma unroll
        for (int r = 0; r < 4; ++r) {
            if (kt == 3 && r > 0) {
#pragma unroll
                for (int qt = 0; qt < 4; ++qt) S[qt][kt][r] = -1e30f;
                continue;
            }
            int key = kt * 16 + lb * 4 + r;
            int kc  = key < 49 ? key : 48;
            int i2  = kc / 7, j2 = kc - 7 * i2;
            int r2  = (wh  < 7) ? 0 : ((i2 < 4) ? 1 : 2);
            int c2  = (wwp < 7) ? 0 : ((j2 < 4) ? 1 : 2);
#pragma unroll
            for (int qt = 0; qt < 4; ++qt) {
                float bv  = rpb[(((i1[qt] - i2 + 6) * 13 + (j1[qt] - j2 + 6)) << 2) + h];
                float val = S[qt][kt][r] * scale + bv;
                if (edge && ((r1[qt] != r2) | (c1[qt] != c2))) val -= 100.f;
                if (kt == 3 && lb > 0) val = -1e30f;
                S[qt][kt][r] = val;
            }
        }
    }

    float inv[4];
#pragma unroll
    for (int qt = 0; qt < 4; ++qt) {
        float mx = -3e38f;
#pragma unroll
        for (int kt = 0; kt < 4; ++kt)
#pragma unroll
            for (int r = 0; r < 4; ++r) mx = fmaxf(mx, S[qt][kt][r]);
        mx = fmaxf(mx, __shfl_xor(mx, 16));
        mx = fmaxf(mx, __shfl_xor(mx, 32));
        float sm = 0.f;
#pragma unroll
        for (int kt = 0; kt < 4; ++kt)
#pragma unroll
            for (int r = 0; r < 4; ++r) {
                float e = __expf(S[qt][kt][r] - mx);
                S[qt][kt][r] = e;
                sm += e;
            }
        sm += __shfl_xor(sm, 16);
        sm += __shfl_xor(sm, 32);
        inv[qt] = 1.f / sm;
    }

    unsigned int w_[4][4][2];
#pragma unroll
    for (int qt = 0; qt < 4; ++qt)
#pragma unroll
        for (int t = 0; t < 4; ++t) {
            w_[qt][t][0] = pk2(S[qt][t][0], S[qt][t][1]);
            w_[qt][t][1] = pk2(S[qt][t][2], S[qt][t][3]);
        }

    int srcA = la + (((2 * lb)     & 3) << 4);
    int srcB = la + (((2 * lb + 1) & 3) << 4);
    bool hiT = (lb >> 1) & 1;

    f32x4 O[2][4];
#pragma unroll
    for (int dt = 0; dt < 2; ++dt)
#pragma unroll
        for (int qt = 0; qt < 4; ++qt) O[dt][qt] = (f32x4){0.f, 0.f, 0.f, 0.f};

    const bf16_t* vrow = vT + ((long)win * 128 + h * 32) * VSTR;
#pragma unroll
    for (int kk = 0; kk < 2; ++kk) {
        bf16x8 vf[2];
#pragma unroll
        for (int dt = 0; dt < 2; ++dt)
            vf[dt] = *reinterpret_cast<const bf16x8*>(
                vrow + (long)(dt * 16 + la) * VSTR + kk * 32 + lb * 8);
        int tl = kk * 2;
#pragma unroll
        for (int qt = 0; qt < 4; ++qt) {
            unsigned int a0 = __shfl(w_[qt][tl][0],     srcA);
            unsigned int b0 = __shfl(w_[qt][tl + 1][0], srcA);
            unsigned int a1 = __shfl(w_[qt][tl][1],     srcA);
            unsigned int b1 = __shfl(w_[qt][tl + 1][1], srcA);
            unsigned int a2 = __shfl(w_[qt][tl][0],     srcB);
            unsigned int b2 = __shfl(w_[qt][tl + 1][0], srcB);
            unsigned int a3 = __shfl(w_[qt][tl][1],     srcB);
            unsigned int b3 = __shfl(w_[qt][tl + 1][1], srcB);
            u32x4 uu = { hiT ? b0 : a0, hiT ? b1 : a1, hiT ? b2 : a2, hiT ? b3 : a3 };
            bf16x8 pf = __builtin_bit_cast(bf16x8, uu);
#pragma unroll
            for (int dt = 0; dt < 2; ++dt)
                O[dt][qt] = __builtin_amdgcn_mfma_f32_16x16x32_bf16(vf[dt], pf, O[dt][qt], 0, 0, 0);
        }
    }

    // ---- normalized O -> LDS (each wave owns cols h*32..h*32+31) ----
#pragma unroll
    for (int qt = 0; qt < 4; ++qt) {
        int q = qt * 16 + la;
        if (q < 49) {
            float iv = inv[qt];
#pragma unroll
            for (int dt = 0; dt < 2; ++dt) {
                unsigned int s0 = pk2(O[dt][qt][0] * iv, O[dt][qt][1] * iv);
                unsigned int s1 = pk2(O[dt][qt][2] * iv, O[dt][qt][3] * iv);
                uint2 st = {s0, s1};
                *reinterpret_cast<uint2*>(&attw[q][h * 32 + dt * 16 + lb * 4]) = st;
            }
        }
    }
    __syncthreads();

    // ---- proj: wave h computes C[q=0..63][n=h*32..h*32+31] ----
    int n0 = h * 32;
    f32x4 pacc[4][2];
#pragma unroll
    for (int nt = 0; nt < 2; ++nt) {
        float bv = projb[n0 + nt * 16 + la];
#pragma unroll
        for (int s = 0; s < 4; ++s) pacc[s][nt] = (f32x4){bv, bv, bv, bv};
    }
#pragma unroll
    for (int kt = 0; kt < 4; ++kt) {
        bf16x8 ar[4];
#pragma unroll
        for (int s = 0; s < 4; ++s)
            ar[s] = *reinterpret_cast<const bf16x8*>(&attw[s * 16 + la][kt * 32 + lb * 8]);
#pragma unroll
        for (int nt = 0; nt < 2; ++nt) {
            bf16x8 br = *reinterpret_cast<const bf16x8*>(
                projwt + (long)(n0 + nt * 16 + la) * 128 + kt * 32 + lb * 8);
#pragma unroll
            for (int s = 0; s < 4; ++s)
                pacc[s][nt] = __builtin_amdgcn_mfma_f32_16x16x32_bf16(
                    ar[s], br, pacc[s][nt], 0, 0, 0);
        }
    }

    // ---- epilogue: window-reverse + unshift + x residual -> f32 y ----
#pragma unroll
    for (int s = 0; s < 4; ++s) {
#pragma unroll
        for (int r = 0; r < 4; ++r) {
            int q = s * 16 + lb * 4 + r;
            if (q < 49) {
                long to = win_to_tok(win * 49 + q);
#pragma unroll
                for (int nt = 0; nt < 2; ++nt) {
                    int col = n0 + nt * 16 + la;
                    y[to * C_ + col] = pacc[s][nt][r] + x[to * C_ + col];
                }
            }
        }
    }
}

// ---------------------------------------------------------------------------
// Fused MLP v7 = v6 with single 32 KB LDS buffer (stage -> barrier ->
// compute -> barrier per chunk) + __launch_bounds__(256,4): 4 blocks/CU,
// 16 waves/CU (2x occupancy vs v6). XOR-swizzled LDS rows.
// ---------------------------------------------------------------------------
__global__ __launch_bounds__(256, 4) void mlp_fused(const float* __restrict__ y,
                                                    const float* __restrict__ g,
                                                    const float* __restrict__ b,
                                                    const bf16_t* __restrict__ w1t,
                                                    const float* __restrict__ b1,
                                                    const bf16_t* __restrict__ w2t,
                                                    const float* __restrict__ b2,
                                                    float* __restrict__ out)
{
    __shared__ uint4 ldsq[2048];             // 32 KB: [W1c 16KB | W2c 16KB]
    int tid  = threadIdx.x;
    int lane = tid & 63;
    int la = lane & 15, lb = lane >> 4;
    int m0 = (blockIdx.x * 4 + (tid >> 6)) * 32;

    auto stage = [&](int c) {
        char* d1 = (char*)&ldsq[0];
        const char* s1 = (const char*)w1t + (size_t)c * 16384;
#pragma unroll
        for (int i = 0; i < 4; ++i) {
            int idx = i * 256 + tid;             // 0..1023, 16B units
            int row = idx >> 4, colb = (idx & 15) * 16;
            uint4 v = *reinterpret_cast<const uint4*>(s1 + idx * 16);
            *reinterpret_cast<uint4*>(d1 + row * 256 + (colb ^ ((row & 7) << 4))) = v;
        }
        char* d2 = (char*)&ldsq[1024];
        const char* s2 = (const char*)w2t + (size_t)c * 128;
#pragma unroll
        for (int i = 0; i < 4; ++i) {
            int idx = i * 256 + tid;             // 0..1023
            int row = idx >> 3, colb = (idx & 7) * 16;
            uint4 v = *reinterpret_cast<const uint4*>(s2 + (size_t)row * 1024 + colb);
            *reinterpret_cast<uint4*>(d2 + row * 128 + (colb ^ ((row & 7) << 4))) = v;
        }
    };

    // ---- LN2 -> fragments for 2 row-subtiles (m = s*16+la, k = kt*32+lb*8+j)
    bf16x8 af[2][4];
#pragma unroll
    for (int s = 0; s < 2; ++s) {
        const float* yr = y + (long)(m0 + s * 16 + la) * C_;
        float vals[4][8];
        float sm = 0.f, qs = 0.f;
#pragma unroll
        for (int kt = 0; kt < 4; ++kt) {
            f32x4 u0 = *reinterpret_cast<const f32x4*>(yr + kt * 32 + lb * 8);
            f32x4 u1 = *reinterpret_cast<const f32x4*>(yr + kt * 32 + lb * 8 + 4);
#pragma unroll
            for (int j = 0; j < 4; ++j) { vals[kt][j] = u0[j]; vals[kt][4 + j] = u1[j]; }
#pragma unroll
            for (int j = 0; j < 8; ++j) { sm += vals[kt][j]; qs += vals[kt][j] * vals[kt][j]; }
        }
        sm += __shfl_xor(sm, 16); sm += __shfl_xor(sm, 32);
        qs += __shfl_xor(qs, 16); qs += __shfl_xor(qs, 32);
        float mean = sm * (1.f / 128.f);
        float rstd = rsqrtf(qs * (1.f / 128.f) - mean * mean + 1e-5f);
#pragma unroll
        for (int kt = 0; kt < 4; ++kt)
#pragma unroll
            for (int j = 0; j < 8; ++j) {
                int col = kt * 32 + lb * 8 + j;
                af[s][kt][j] = (__bf16)((vals[kt][j] - mean) * rstd * g[col] + b[col]);
            }
    }

    // ---- out^T accumulators: acc[s][nt2]: out[m=s*16+la][n2=nt2*16+lb*4+r]
    f32x4 acc[2][8];
#pragma unroll
    for (int nt2 = 0; nt2 < 8; ++nt2) {
        f32x4 bv = *reinterpret_cast<const f32x4*>(b2 + nt2 * 16 + lb * 4);
#pragma unroll
        for (int s = 0; s < 2; ++s) acc[s][nt2] = bv;
    }

    int srcA = la + (((2 * lb)     & 3) << 4);
    int srcB = la + (((2 * lb + 1) & 3) << 4);
    bool hiT = (lb >> 1) & 1;

    for (int c = 0; c < 8; ++c) {
        stage(c);
        __syncthreads();

        const char* L1 = (const char*)&ldsq[0];
        const char* L2 = (const char*)&ldsq[1024];

        // ---- fc1 chunk TRANSPOSED from LDS: hT[n1][m] ----
        f32x4 hacc[2][4];
#pragma unroll
        for (int nt = 0; nt < 4; ++nt) {
            f32x4 bv = *reinterpret_cast<const f32x4*>(b1 + c * 64 + nt * 16 + lb * 4);
#pragma unroll
            for (int s = 0; s < 2; ++s) hacc[s][nt] = bv;
        }
#pragma unroll
        for (int kt = 0; kt < 4; ++kt)
#pragma unroll
            for (int nt = 0; nt < 4; ++nt) {
                int row = nt * 16 + la;
                bf16x8 w1f = *reinterpret_cast<const bf16x8*>(
                    L1 + row * 256 + ((kt * 64 + lb * 16) ^ ((row & 7) << 4)));
#pragma unroll
                for (int s = 0; s < 2; ++s)
                    hacc[s][nt] = __builtin_amdgcn_mfma_f32_16x16x32_bf16(
                        w1f, af[s][kt], hacc[s][nt], 0, 0, 0);
            }
        // ---- fast GELU + pack ----
        unsigned int wpk[2][4][2];
#pragma unroll
        for (int s = 0; s < 2; ++s)
#pragma unroll
            for (int t = 0; t < 4; ++t) {
                f32x4 hv = hacc[s][t];
#pragma unroll
                for (int r = 0; r < 4; ++r) hv[r] = gelu_f(hv[r]);
                wpk[s][t][0] = pk2(hv[0], hv[1]);
                wpk[s][t][1] = pk2(hv[2], hv[3]);
            }
        // ---- fc2 chunk ----
#pragma unroll
        for (int kk = 0; kk < 2; ++kk) {
            int tl = kk * 2;
#pragma unroll
            for (int s = 0; s < 2; ++s) {
                unsigned int a0 = __shfl(wpk[s][tl][0],     srcA);
                unsigned int b0 = __shfl(wpk[s][tl + 1][0], srcA);
                unsigned int a1 = __shfl(wpk[s][tl][1],     srcA);
                unsigned int b1v = __shfl(wpk[s][tl + 1][1], srcA);
                unsigned int a2 = __shfl(wpk[s][tl][0],     srcB);
                unsigned int b2v = __shfl(wpk[s][tl + 1][0], srcB);
                unsigned int a3 = __shfl(wpk[s][tl][1],     srcB);
                unsigned int b3v = __shfl(wpk[s][tl + 1][1], srcB);
                u32x4 uu = { hiT ? b0 : a0, hiT ? b1v : a1, hiT ? b2v : a2, hiT ? b3v : a3 };
                bf16x8 pf = __builtin_bit_cast(bf16x8, uu);
#pragma unroll
                for (int nt2 = 0; nt2 < 8; ++nt2) {
                    int row2 = nt2 * 16 + la;
                    bf16x8 w2f = *reinterpret_cast<const bf16x8*>(
                        L2 + row2 * 128 + ((kk * 64 + lb * 16) ^ ((row2 & 7) << 4)));
                    acc[s][nt2] = __builtin_amdgcn_mfma_f32_16x16x32_bf16(
                        w2f, pf, acc[s][nt2], 0, 0, 0);
                }
            }
        }
        __syncthreads();   // all waves done reading before next stage
    }

    // ---- epilogue: + y residual -> out (in-place safe: exclusive rows) ----
#pragma unroll
    for (int s = 0; s < 2; ++s) {
        long m = m0 + s * 16 + la;
        const float* yrow = y + m * C_;
        float* orow = out + m * C_;
#pragma unroll
        for (int nt2 = 0; nt2 < 8; ++nt2) {
            int n2 = nt2 * 16 + lb * 4;
            f32x4 res = *reinterpret_cast<const f32x4*>(yrow + n2);
            f32x4 val = acc[s][nt2] + res;
            *reinterpret_cast<f32x4*>(orow + n2) = val;
        }
    }
}

// ---------------------------------------------------------------------------
extern "C" void kernel_launch(void* const* d_in, const int* in_sizes, int n_in,
                              void* d_out, int out_size, void* d_ws, size_t ws_size,
                              hipStream_t stream)
{
    (void)in_sizes; (void)n_in; (void)out_size;

    const float* x      = (const float*)d_in[0];
    const float* n1g    = (const float*)d_in[1];
    const float* n1b    = (const float*)d_in[2];
    const float* qkv_w  = (const float*)d_in[3];
    const float* qkv_b  = (const float*)d_in[4];
    const float* proj_w = (const float*)d_in[5];
    const float* proj_b = (const float*)d_in[6];
    const float* rpb    = (const float*)d_in[7];
    const float* n2g    = (const float*)d_in[8];
    const float* n2b    = (const float*)d_in[9];
    const float* fc1_w  = (const float*)d_in[10];
    const float* fc1_b  = (const float*)d_in[11];
    const float* fc2_w  = (const float*)d_in[12];
    const float* fc2_b  = (const float*)d_in[13];

    char* ws = (char*)d_ws;

    const size_t qk_sz = (size_t)M_ * 256 * 2;               // 102,760,448
    const size_t vt_sz = (size_t)NWIN * 128 * VSTR * 2;      //  58,720,256
    const size_t at_sz = (size_t)M_ * 128 * 2;               //  51,380,224 (reserved)
    const size_t w_off = qk_sz + vt_sz + at_sz;
    const size_t w_sz  = (size_t)(128 * 384 + 128 * 128 + 128 * 512 + 512 * 128) * 2;
    const size_t need  = w_off + w_sz;                       // ~213.6 MB (proven fit)

    if (need > ws_size) {
        sentinel_kernel<<<1, 256, 0, stream>>>((float*)d_out);
        return;
    }

    bf16_t* qkb  = (bf16_t*)ws;
    bf16_t* vT   = (bf16_t*)(ws + qk_sz);
    bf16_t* qkv_wt  = (bf16_t*)(ws + w_off);
    bf16_t* proj_wt = qkv_wt + 128 * 384;
    bf16_t* fc1_wt  = proj_wt + 128 * 128;
    bf16_t* fc2_wt  = fc1_wt + 128 * 512;

    float* y = (float*)d_out;

    transpose_w<<<(128 * 384 + 255) / 256, 256, 0, stream>>>(qkv_w, qkv_wt, 128, 384);
    transpose_w<<<(128 * 128 + 255) / 256, 256, 0, stream>>>(proj_w, proj_wt, 128, 128);
    transpose_w<<<(128 * 512 + 255) / 256, 256, 0, stream>>>(fc1_w, fc1_wt, 128, 512);
    transpose_w<<<(512 * 128 + 255) / 256, 256, 0, stream>>>(fc2_w, fc2_wt, 512, 128);

    // zero vT pad keys (NaN safety for PV fragments)
    zpad_kernel<<<(NWIN * 128 * 7 + 255) / 256, 256, 0, stream>>>(vT);
    // LN1 + shift/window gather fused into QKV projection
    gemm2<128, 384, 1, 0><<<dim3(M_ / 256, 6), 256, 0, stream>>>(
        x, n1g, n1b, qkv_wt, qkv_b, qkb, nullptr, vT);
    // MFMA attention + fused proj + window-reverse + x residual -> f32 y
    attn_mfma<<<NWIN, 256, 0, stream>>>(qkb, vT, rpb, proj_wt, proj_b, x, y);
    // fused LN2 + fc1 + GELU + fc2 + residual (in-place on d_out)
    mlp_fused<<<M_ / 128, 256, 0, stream>>>(
        y, n2g, n2b, fc1_wt, fc1_b, fc2_wt, fc2_b, y);
}

// Round 13
// 517.644 us; speedup vs baseline: 1.7251x; 1.1502x over previous
//
#include <hip/hip_runtime.h>
#include <hip/hip_bf16.h>
#include <math.h>

typedef __bf16 bf16x8 __attribute__((ext_vector_type(8)));
typedef float  f32x4  __attribute__((ext_vector_type(4)));
typedef unsigned int u32x4 __attribute__((ext_vector_type(4)));
typedef __hip_bfloat16 bf16_t;

static constexpr int C_    = 128;
static constexpr int L_    = 56 * 56;        // tokens per image
static constexpr int M_    = 64 * L_;        // 200704 total tokens
static constexpr int NWIN  = 64 * 64;        // 4096 windows
static constexpr int VSTR  = 56;             // vT padded key stride

// map windowed token index tw -> unwindowed token index (shift+window bijection)
__device__ inline long win_to_tok(int tw)
{
    int win = tw / 49, n = tw % 49;
    int bb  = win >> 6, wi = win & 63;
    int wh  = wi >> 3, wwp = wi & 7;
    int hs  = wh * 7 + n / 7;
    int wsv = wwp * 7 + n % 7;
    int hh  = (hs + 3) % 56;          // un-shift
    int ww  = (wsv + 3) % 56;
    return (long)bb * L_ + hh * 56 + ww;
}

__device__ inline unsigned int pk2(float lo, float hi)
{
    unsigned short a = __builtin_bit_cast(unsigned short, (__bf16)lo);
    unsigned short b = __builtin_bit_cast(unsigned short, (__bf16)hi);
    return (unsigned int)a | ((unsigned int)b << 16);
}

// tanh-form GELU: ~8 VALU ops, |err| <= ~3e-3 (threshold is 0.11).
__device__ inline float gelu_f(float x)
{
    float u = 0.7978845608f * x * (1.f + 0.044715f * x * x);
    float e = __expf(2.f * fminf(u, 15.f));
    return x * e * __builtin_amdgcn_rcpf(e + 1.f);
}

__global__ void sentinel_kernel(float* o) { o[threadIdx.x] = 1e9f; }

// ---------------------------------------------------------------------------
__global__ void transpose_w(const float* __restrict__ w, bf16_t* __restrict__ wt,
                            int K, int N)
{
    int i = blockIdx.x * 256 + threadIdx.x;
    if (i >= K * N) return;
    int k = i / N, n = i % N;
    wt[(long)n * K + k] = __float2bfloat16(w[i]);
}

// zero vT pad keys 49..55 for all (win, d)
__global__ void zpad_kernel(bf16_t* __restrict__ vT)
{
    long i = (long)blockIdx.x * 256 + threadIdx.x;
    if (i >= (long)NWIN * 128 * 7) return;
    long row = i / 7;
    int  k   = 49 + (int)(i % 7);
    vT[row * VSTR + k] = __float2bfloat16(0.f);
}

// ---------------------------------------------------------------------------
// Fused LN1 + QKV projection, x read ONCE.
// grid = M/64, block = 4 waves. Stage: each wave LN1s 16 rows -> LDS
// xn[64][256B] (XOR-swizzled rows). Compute: wave w does a 64x96 tile
// (cols w*96..w*96+95) with A from LDS, B (qkv_wt [384][128]) from L2.
// Epilogue: cols<256 -> qk[token][256]; cols>=256 -> vT[win][d][key].
// ---------------------------------------------------------------------------
__global__ __launch_bounds__(256) void qkv_fused(const float* __restrict__ x,
                                                 const float* __restrict__ lng,
                                                 const float* __restrict__ lnb,
                                                 const bf16_t* __restrict__ Bt,
                                                 const float*  __restrict__ bias,
                                                 bf16_t* __restrict__ qk,
                                                 bf16_t* __restrict__ vT)
{
    __shared__ char xn[64 * 256];            // 16 KB
    int tid  = threadIdx.x;
    int wave = tid >> 6;
    int lane = tid & 63;
    int la = lane & 15, lb = lane >> 4;
    int m0 = blockIdx.x * 64;

    // ---- stage: LN1 of row (wave*16+la) -> LDS ----
    {
        int row = wave * 16 + la;
        long src = win_to_tok(m0 + row);
        const float* xr = x + src * C_;
        float vals[4][8];
        float sm = 0.f, qs = 0.f;
#pragma unroll
        for (int kt = 0; kt < 4; ++kt) {
            f32x4 u0 = *reinterpret_cast<const f32x4*>(xr + kt * 32 + lb * 8);
            f32x4 u1 = *reinterpret_cast<const f32x4*>(xr + kt * 32 + lb * 8 + 4);
#pragma unroll
            for (int j = 0; j < 4; ++j) { vals[kt][j] = u0[j]; vals[kt][4 + j] = u1[j]; }
#pragma unroll
            for (int j = 0; j < 8; ++j) { sm += vals[kt][j]; qs += vals[kt][j] * vals[kt][j]; }
        }
        sm += __shfl_xor(sm, 16); sm += __shfl_xor(sm, 32);
        qs += __shfl_xor(qs, 16); qs += __shfl_xor(qs, 32);
        float mean = sm * (1.f / 128.f);
        float rstd = rsqrtf(qs * (1.f / 128.f) - mean * mean + 1e-5f);
#pragma unroll
        for (int kt = 0; kt < 4; ++kt) {
            bf16x8 v8;
#pragma unroll
            for (int j = 0; j < 8; ++j) {
                int col = kt * 32 + lb * 8 + j;
                v8[j] = (__bf16)((vals[kt][j] - mean) * rstd * lng[col] + lnb[col]);
            }
            int colb = kt * 64 + lb * 16;
            *reinterpret_cast<bf16x8*>(xn + row * 256 + (colb ^ ((row & 7) << 4))) = v8;
        }
    }
    __syncthreads();

    // ---- compute: 64 rows x 96 cols per wave ----
    int c0 = wave * 96;
    f32x4 acc[4][6];
#pragma unroll
    for (int nt = 0; nt < 6; ++nt) {
        float bv = bias[c0 + nt * 16 + la];
#pragma unroll
        for (int s = 0; s < 4; ++s) acc[s][nt] = (f32x4){bv, bv, bv, bv};
    }

#pragma unroll
    for (int kt = 0; kt < 4; ++kt) {
        bf16x8 ar[4];
#pragma unroll
        for (int s = 0; s < 4; ++s) {
            int row = s * 16 + la;
            ar[s] = *reinterpret_cast<const bf16x8*>(
                xn + row * 256 + ((kt * 64 + lb * 16) ^ ((row & 7) << 4)));
        }
#pragma unroll
        for (int nt = 0; nt < 6; ++nt) {
            bf16x8 br = *reinterpret_cast<const bf16x8*>(
                Bt + (long)(c0 + nt * 16 + la) * 128 + kt * 32 + lb * 8);
#pragma unroll
            for (int s = 0; s < 4; ++s)
                acc[s][nt] = __builtin_amdgcn_mfma_f32_16x16x32_bf16(
                    ar[s], br, acc[s][nt], 0, 0, 0);
        }
    }

    // ---- epilogue ----
#pragma unroll
    for (int s = 0; s < 4; ++s) {
#pragma unroll
        for (int r = 0; r < 4; ++r) {
            int row = m0 + s * 16 + lb * 4 + r;
            int win = row / 49, key = row - win * 49;
#pragma unroll
            for (int nt = 0; nt < 6; ++nt) {
                int col = c0 + nt * 16 + la;
                float v = acc[s][nt][r];
                if (col < 256)
                    qk[(long)row * 256 + col] = __float2bfloat16(v);
                else
                    vT[((long)win * 128 + (col - 256)) * VSTR + key] = __float2bfloat16(v);
            }
        }
    }
}

// ---------------------------------------------------------------------------
// MFMA windowed attention + fused proj + window-reverse + x residual.
// One block per window, one wave per head.
// ---------------------------------------------------------------------------
__global__ __launch_bounds__(256) void attn_mfma(const bf16_t* __restrict__ qk,
                                                 const bf16_t* __restrict__ vT,
                                                 const float*  __restrict__ rpb,
                                                 const bf16_t* __restrict__ projwt,
                                                 const float*  __restrict__ projb,
                                                 const float*  __restrict__ x,
                                                 float* __restrict__ y)
{
    int win  = blockIdx.x;
    int h    = threadIdx.x >> 6;
    int lane = threadIdx.x & 63;
    int la = lane & 15, lb = lane >> 4;

    __shared__ __bf16 attw[49][152];

    const bf16_t* qkw = qk + (long)win * 49 * 256;

    bf16x8 kf[4], qf[4];
#pragma unroll
    for (int t = 0; t < 4; ++t) {
        kf[t] = *reinterpret_cast<const bf16x8*>(qkw + (long)(t * 16 + la) * 256 + 128 + h * 32 + lb * 8);
        qf[t] = *reinterpret_cast<const bf16x8*>(qkw + (long)(t * 16 + la) * 256 +       h * 32 + lb * 8);
    }

    f32x4 S[4][4];
#pragma unroll
    for (int qt = 0; qt < 4; ++qt)
#pragma unroll
        for (int kt = 0; kt < 4; ++kt)
            S[qt][kt] = __builtin_amdgcn_mfma_f32_16x16x32_bf16(
                kf[kt], qf[qt], (f32x4){0.f, 0.f, 0.f, 0.f}, 0, 0, 0);

    const float scale = 0.17677669529663687f;   // 1/sqrt(32)
    int wi  = win & 63;
    int wh  = wi >> 3, wwp = wi & 7;
    bool edge = (wh == 7) || (wwp == 7);

    int i1[4], j1[4], r1[4], c1[4];
#pragma unroll
    for (int qt = 0; qt < 4; ++qt) {
        int q  = qt * 16 + la;
        int qc = q < 49 ? q : 48;
        i1[qt] = qc / 7; j1[qt] = qc - 7 * i1[qt];
        r1[qt] = (wh  < 7) ? 0 : ((i1[qt] < 4) ? 1 : 2);
        c1[qt] = (wwp < 7) ? 0 : ((j1[qt] < 4) ? 1 : 2);
    }

#pragma unroll
    for (int kt = 0; kt < 4; ++kt) {
#pragma unroll
        for (int r = 0; r < 4; ++r) {
            if (kt == 3 && r > 0) {
#pragma unroll
                for (int qt = 0; qt < 4; ++qt) S[qt][kt][r] = -1e30f;
                continue;
            }
            int key = kt * 16 + lb * 4 + r;
            int kc  = key < 49 ? key : 48;
            int i2  = kc / 7, j2 = kc - 7 * i2;
            int r2  = (wh  < 7) ? 0 : ((i2 < 4) ? 1 : 2);
            int c2  = (wwp < 7) ? 0 : ((j2 < 4) ? 1 : 2);
#pragma unroll
            for (int qt = 0; qt < 4; ++qt) {
                float bv  = rpb[(((i1[qt] - i2 + 6) * 13 + (j1[qt] - j2 + 6)) << 2) + h];
                float val = S[qt][kt][r] * scale + bv;
                if (edge && ((r1[qt] != r2) | (c1[qt] != c2))) val -= 100.f;
                if (kt == 3 && lb > 0) val = -1e30f;
                S[qt][kt][r] = val;
            }
        }
    }

    float inv[4];
#pragma unroll
    for (int qt = 0; qt < 4; ++qt) {
        float mx = -3e38f;
#pragma unroll
        for (int kt = 0; kt < 4; ++kt)
#pragma unroll
            for (int r = 0; r < 4; ++r) mx = fmaxf(mx, S[qt][kt][r]);
        mx = fmaxf(mx, __shfl_xor(mx, 16));
        mx = fmaxf(mx, __shfl_xor(mx, 32));
        float sm = 0.f;
#pragma unroll
        for (int kt = 0; kt < 4; ++kt)
#pragma unroll
            for (int r = 0; r < 4; ++r) {
                float e = __expf(S[qt][kt][r] - mx);
                S[qt][kt][r] = e;
                sm += e;
            }
        sm += __shfl_xor(sm, 16);
        sm += __shfl_xor(sm, 32);
        inv[qt] = 1.f / sm;
    }

    unsigned int w_[4][4][2];
#pragma unroll
    for (int qt = 0; qt < 4; ++qt)
#pragma unroll
        for (int t = 0; t < 4; ++t) {
            w_[qt][t][0] = pk2(S[qt][t][0], S[qt][t][1]);
            w_[qt][t][1] = pk2(S[qt][t][2], S[qt][t][3]);
        }

    int srcA = la + (((2 * lb)     & 3) << 4);
    int srcB = la + (((2 * lb + 1) & 3) << 4);
    bool hiT = (lb >> 1) & 1;

    f32x4 O[2][4];
#pragma unroll
    for (int dt = 0; dt < 2; ++dt)
#pragma unroll
        for (int qt = 0; qt < 4; ++qt) O[dt][qt] = (f32x4){0.f, 0.f, 0.f, 0.f};

    const bf16_t* vrow = vT + ((long)win * 128 + h * 32) * VSTR;
#pragma unroll
    for (int kk = 0; kk < 2; ++kk) {
        bf16x8 vf[2];
#pragma unroll
        for (int dt = 0; dt < 2; ++dt)
            vf[dt] = *reinterpret_cast<const bf16x8*>(
                vrow + (long)(dt * 16 + la) * VSTR + kk * 32 + lb * 8);
        int tl = kk * 2;
#pragma unroll
        for (int qt = 0; qt < 4; ++qt) {
            unsigned int a0 = __shfl(w_[qt][tl][0],     srcA);
            unsigned int b0 = __shfl(w_[qt][tl + 1][0], srcA);
            unsigned int a1 = __shfl(w_[qt][tl][1],     srcA);
            unsigned int b1 = __shfl(w_[qt][tl + 1][1], srcA);
            unsigned int a2 = __shfl(w_[qt][tl][0],     srcB);
            unsigned int b2 = __shfl(w_[qt][tl + 1][0], srcB);
            unsigned int a3 = __shfl(w_[qt][tl][1],     srcB);
            unsigned int b3 = __shfl(w_[qt][tl + 1][1], srcB);
            u32x4 uu = { hiT ? b0 : a0, hiT ? b1 : a1, hiT ? b2 : a2, hiT ? b3 : a3 };
            bf16x8 pf = __builtin_bit_cast(bf16x8, uu);
#pragma unroll
            for (int dt = 0; dt < 2; ++dt)
                O[dt][qt] = __builtin_amdgcn_mfma_f32_16x16x32_bf16(vf[dt], pf, O[dt][qt], 0, 0, 0);
        }
    }

    // ---- normalized O -> LDS (each wave owns cols h*32..h*32+31) ----
#pragma unroll
    for (int qt = 0; qt < 4; ++qt) {
        int q = qt * 16 + la;
        if (q < 49) {
            float iv = inv[qt];
#pragma unroll
            for (int dt = 0; dt < 2; ++dt) {
                unsigned int s0 = pk2(O[dt][qt][0] * iv, O[dt][qt][1] * iv);
                unsigned int s1 = pk2(O[dt][qt][2] * iv, O[dt][qt][3] * iv);
                uint2 st = {s0, s1};
                *reinterpret_cast<uint2*>(&attw[q][h * 32 + dt * 16 + lb * 4]) = st;
            }
        }
    }
    __syncthreads();

    // ---- proj: wave h computes C[q=0..63][n=h*32..h*32+31] ----
    int n0 = h * 32;
    f32x4 pacc[4][2];
#pragma unroll
    for (int nt = 0; nt < 2; ++nt) {
        float bv = projb[n0 + nt * 16 + la];
#pragma unroll
        for (int s = 0; s < 4; ++s) pacc[s][nt] = (f32x4){bv, bv, bv, bv};
    }
#pragma unroll
    for (int kt = 0; kt < 4; ++kt) {
        bf16x8 ar[4];
#pragma unroll
        for (int s = 0; s < 4; ++s)
            ar[s] = *reinterpret_cast<const bf16x8*>(&attw[s * 16 + la][kt * 32 + lb * 8]);
#pragma unroll
        for (int nt = 0; nt < 2; ++nt) {
            bf16x8 br = *reinterpret_cast<const bf16x8*>(
                projwt + (long)(n0 + nt * 16 + la) * 128 + kt * 32 + lb * 8);
#pragma unroll
            for (int s = 0; s < 4; ++s)
                pacc[s][nt] = __builtin_amdgcn_mfma_f32_16x16x32_bf16(
                    ar[s], br, pacc[s][nt], 0, 0, 0);
        }
    }

    // ---- epilogue: window-reverse + unshift + x residual -> f32 y ----
#pragma unroll
    for (int s = 0; s < 4; ++s) {
#pragma unroll
        for (int r = 0; r < 4; ++r) {
            int q = s * 16 + lb * 4 + r;
            if (q < 49) {
                long to = win_to_tok(win * 49 + q);
#pragma unroll
                for (int nt = 0; nt < 2; ++nt) {
                    int col = n0 + nt * 16 + la;
                    y[to * C_ + col] = pacc[s][nt][r] + x[to * C_ + col];
                }
            }
        }
    }
}

// ---------------------------------------------------------------------------
// Fused MLP v7: single 32 KB LDS buffer (stage -> barrier -> compute ->
// barrier per chunk) + __launch_bounds__(256,4). XOR-swizzled LDS rows.
// ---------------------------------------------------------------------------
__global__ __launch_bounds__(256, 4) void mlp_fused(const float* __restrict__ y,
                                                    const float* __restrict__ g,
                                                    const float* __restrict__ b,
                                                    const bf16_t* __restrict__ w1t,
                                                    const float* __restrict__ b1,
                                                    const bf16_t* __restrict__ w2t,
                                                    const float* __restrict__ b2,
                                                    float* __restrict__ out)
{
    __shared__ uint4 ldsq[2048];             // 32 KB: [W1c 16KB | W2c 16KB]
    int tid  = threadIdx.x;
    int lane = tid & 63;
    int la = lane & 15, lb = lane >> 4;
    int m0 = (blockIdx.x * 4 + (tid >> 6)) * 32;

    auto stage = [&](int c) {
        char* d1 = (char*)&ldsq[0];
        const char* s1 = (const char*)w1t + (size_t)c * 16384;
#pragma unroll
        for (int i = 0; i < 4; ++i) {
            int idx = i * 256 + tid;             // 0..1023, 16B units
            int row = idx >> 4, colb = (idx & 15) * 16;
            uint4 v = *reinterpret_cast<const uint4*>(s1 + idx * 16);
            *reinterpret_cast<uint4*>(d1 + row * 256 + (colb ^ ((row & 7) << 4))) = v;
        }
        char* d2 = (char*)&ldsq[1024];
        const char* s2 = (const char*)w2t + (size_t)c * 128;
#pragma unroll
        for (int i = 0; i < 4; ++i) {
            int idx = i * 256 + tid;             // 0..1023
            int row = idx >> 3, colb = (idx & 7) * 16;
            uint4 v = *reinterpret_cast<const uint4*>(s2 + (size_t)row * 1024 + colb);
            *reinterpret_cast<uint4*>(d2 + row * 128 + (colb ^ ((row & 7) << 4))) = v;
        }
    };

    // ---- LN2 -> fragments for 2 row-subtiles (m = s*16+la, k = kt*32+lb*8+j)
    bf16x8 af[2][4];
#pragma unroll
    for (int s = 0; s < 2; ++s) {
        const float* yr = y + (long)(m0 + s * 16 + la) * C_;
        float vals[4][8];
        float sm = 0.f, qs = 0.f;
#pragma unroll
        for (int kt = 0; kt < 4; ++kt) {
            f32x4 u0 = *reinterpret_cast<const f32x4*>(yr + kt * 32 + lb * 8);
            f32x4 u1 = *reinterpret_cast<const f32x4*>(yr + kt * 32 + lb * 8 + 4);
#pragma unroll
            for (int j = 0; j < 4; ++j) { vals[kt][j] = u0[j]; vals[kt][4 + j] = u1[j]; }
#pragma unroll
            for (int j = 0; j < 8; ++j) { sm += vals[kt][j]; qs += vals[kt][j] * vals[kt][j]; }
        }
        sm += __shfl_xor(sm, 16); sm += __shfl_xor(sm, 32);
        qs += __shfl_xor(qs, 16); qs += __shfl_xor(qs, 32);
        float mean = sm * (1.f / 128.f);
        float rstd = rsqrtf(qs * (1.f / 128.f) - mean * mean + 1e-5f);
#pragma unroll
        for (int kt = 0; kt < 4; ++kt)
#pragma unroll
            for (int j = 0; j < 8; ++j) {
                int col = kt * 32 + lb * 8 + j;
                af[s][kt][j] = (__bf16)((vals[kt][j] - mean) * rstd * g[col] + b[col]);
            }
    }

    // ---- out^T accumulators: acc[s][nt2]: out[m=s*16+la][n2=nt2*16+lb*4+r]
    f32x4 acc[2][8];
#pragma unroll
    for (int nt2 = 0; nt2 < 8; ++nt2) {
        f32x4 bv = *reinterpret_cast<const f32x4*>(b2 + nt2 * 16 + lb * 4);
#pragma unroll
        for (int s = 0; s < 2; ++s) acc[s][nt2] = bv;
    }

    int srcA = la + (((2 * lb)     & 3) << 4);
    int srcB = la + (((2 * lb + 1) & 3) << 4);
    bool hiT = (lb >> 1) & 1;

    for (int c = 0; c < 8; ++c) {
        stage(c);
        __syncthreads();

        const char* L1 = (const char*)&ldsq[0];
        const char* L2 = (const char*)&ldsq[1024];

        // ---- fc1 chunk TRANSPOSED from LDS: hT[n1][m] ----
        f32x4 hacc[2][4];
#pragma unroll
        for (int nt = 0; nt < 4; ++nt) {
            f32x4 bv = *reinterpret_cast<const f32x4*>(b1 + c * 64 + nt * 16 + lb * 4);
#pragma unroll
            for (int s = 0; s < 2; ++s) hacc[s][nt] = bv;
        }
#pragma unroll
        for (int kt = 0; kt < 4; ++kt)
#pragma unroll
            for (int nt = 0; nt < 4; ++nt) {
                int row = nt * 16 + la;
                bf16x8 w1f = *reinterpret_cast<const bf16x8*>(
                    L1 + row * 256 + ((kt * 64 + lb * 16) ^ ((row & 7) << 4)));
#pragma unroll
                for (int s = 0; s < 2; ++s)
                    hacc[s][nt] = __builtin_amdgcn_mfma_f32_16x16x32_bf16(
                        w1f, af[s][kt], hacc[s][nt], 0, 0, 0);
            }
        // ---- fast GELU + pack ----
        unsigned int wpk[2][4][2];
#pragma unroll
        for (int s = 0; s < 2; ++s)
#pragma unroll
            for (int t = 0; t < 4; ++t) {
                f32x4 hv = hacc[s][t];
#pragma unroll
                for (int r = 0; r < 4; ++r) hv[r] = gelu_f(hv[r]);
                wpk[s][t][0] = pk2(hv[0], hv[1]);
                wpk[s][t][1] = pk2(hv[2], hv[3]);
            }
        // ---- fc2 chunk ----
#pragma unroll
        for (int kk = 0; kk < 2; ++kk) {
            int tl = kk * 2;
#pragma unroll
            for (int s = 0; s < 2; ++s) {
                unsigned int a0 = __shfl(wpk[s][tl][0],     srcA);
                unsigned int b0 = __shfl(wpk[s][tl + 1][0], srcA);
                unsigned int a1 = __shfl(wpk[s][tl][1],     srcA);
                unsigned int b1v = __shfl(wpk[s][tl + 1][1], srcA);
                unsigned int a2 = __shfl(wpk[s][tl][0],     srcB);
                unsigned int b2v = __shfl(wpk[s][tl + 1][0], srcB);
                unsigned int a3 = __shfl(wpk[s][tl][1],     srcB);
                unsigned int b3v = __shfl(wpk[s][tl + 1][1], srcB);
                u32x4 uu = { hiT ? b0 : a0, hiT ? b1v : a1, hiT ? b2v : a2, hiT ? b3v : a3 };
                bf16x8 pf = __builtin_bit_cast(bf16x8, uu);
#pragma unroll
                for (int nt2 = 0; nt2 < 8; ++nt2) {
                    int row2 = nt2 * 16 + la;
                    bf16x8 w2f = *reinterpret_cast<const bf16x8*>(
                        L2 + row2 * 128 + ((kk * 64 + lb * 16) ^ ((row2 & 7) << 4)));
                    acc[s][nt2] = __builtin_amdgcn_mfma_f32_16x16x32_bf16(
                        w2f, pf, acc[s][nt2], 0, 0, 0);
                }
            }
        }
        __syncthreads();   // all waves done reading before next stage
    }

    // ---- epilogue: + y residual -> out (in-place safe: exclusive rows) ----
#pragma unroll
    for (int s = 0; s < 2; ++s) {
        long m = m0 + s * 16 + la;
        const float* yrow = y + m * C_;
        float* orow = out + m * C_;
#pragma unroll
        for (int nt2 = 0; nt2 < 8; ++nt2) {
            int n2 = nt2 * 16 + lb * 4;
            f32x4 res = *reinterpret_cast<const f32x4*>(yrow + n2);
            f32x4 val = acc[s][nt2] + res;
            *reinterpret_cast<f32x4*>(orow + n2) = val;
        }
    }
}

// ---------------------------------------------------------------------------
extern "C" void kernel_launch(void* const* d_in, const int* in_sizes, int n_in,
                              void* d_out, int out_size, void* d_ws, size_t ws_size,
                              hipStream_t stream)
{
    (void)in_sizes; (void)n_in; (void)out_size;

    const float* x      = (const float*)d_in[0];
    const float* n1g    = (const float*)d_in[1];
    const float* n1b    = (const float*)d_in[2];
    const float* qkv_w  = (const float*)d_in[3];
    const float* qkv_b  = (const float*)d_in[4];
    const float* proj_w = (const float*)d_in[5];
    const float* proj_b = (const float*)d_in[6];
    const float* rpb    = (const float*)d_in[7];
    const float* n2g    = (const float*)d_in[8];
    const float* n2b    = (const float*)d_in[9];
    const float* fc1_w  = (const float*)d_in[10];
    const float* fc1_b  = (const float*)d_in[11];
    const float* fc2_w  = (const float*)d_in[12];
    const float* fc2_b  = (const float*)d_in[13];

    char* ws = (char*)d_ws;

    const size_t qk_sz = (size_t)M_ * 256 * 2;               // 102,760,448
    const size_t vt_sz = (size_t)NWIN * 128 * VSTR * 2;      //  58,720,256
    const size_t at_sz = (size_t)M_ * 128 * 2;               //  51,380,224 (reserved)
    const size_t w_off = qk_sz + vt_sz + at_sz;
    const size_t w_sz  = (size_t)(128 * 384 + 128 * 128 + 128 * 512 + 512 * 128) * 2;
    const size_t need  = w_off + w_sz;                       // ~213.6 MB (proven fit)

    if (need > ws_size) {
        sentinel_kernel<<<1, 256, 0, stream>>>((float*)d_out);
        return;
    }

    bf16_t* qkb  = (bf16_t*)ws;
    bf16_t* vT   = (bf16_t*)(ws + qk_sz);
    bf16_t* qkv_wt  = (bf16_t*)(ws + w_off);
    bf16_t* proj_wt = qkv_wt + 128 * 384;
    bf16_t* fc1_wt  = proj_wt + 128 * 128;
    bf16_t* fc2_wt  = fc1_wt + 128 * 512;

    float* y = (float*)d_out;

    transpose_w<<<(128 * 384 + 255) / 256, 256, 0, stream>>>(qkv_w, qkv_wt, 128, 384);
    transpose_w<<<(128 * 128 + 255) / 256, 256, 0, stream>>>(proj_w, proj_wt, 128, 128);
    transpose_w<<<(128 * 512 + 255) / 256, 256, 0, stream>>>(fc1_w, fc1_wt, 128, 512);
    transpose_w<<<(512 * 128 + 255) / 256, 256, 0, stream>>>(fc2_w, fc2_wt, 512, 128);

    // zero vT pad keys (NaN safety for PV fragments)
    zpad_kernel<<<(NWIN * 128 * 7 + 255) / 256, 256, 0, stream>>>(vT);
    // LN1 + QKV projection, x read once
    qkv_fused<<<M_ / 64, 256, 0, stream>>>(x, n1g, n1b, qkv_wt, qkv_b, qkb, vT);
    // MFMA attention + fused proj + window-reverse + x residual -> f32 y
    attn_mfma<<<NWIN, 256, 0, stream>>>(qkb, vT, rpb, proj_wt, proj_b, x, y);
    // fused LN2 + fc1 + GELU + fc2 + residual (in-place on d_out)
    mlp_fused<<<M_ / 128, 256, 0, stream>>>(
        y, n2g, n2b, fc1_wt, fc1_b, fc2_wt, fc2_b, y);
}

// Round 14
// 473.006 us; speedup vs baseline: 1.8879x; 1.0944x over previous
//
#include <hip/hip_runtime.h>
#include <hip/hip_bf16.h>
#include <math.h>

typedef __bf16 bf16x8 __attribute__((ext_vector_type(8)));
typedef __bf16 bf16x4 __attribute__((ext_vector_type(4)));
typedef float  f32x4  __attribute__((ext_vector_type(4)));
typedef unsigned int u32x4 __attribute__((ext_vector_type(4)));
typedef __hip_bfloat16 bf16_t;

static constexpr int C_    = 128;
static constexpr int L_    = 56 * 56;        // tokens per image
static constexpr int M_    = 64 * L_;        // 200704 total tokens
static constexpr int NWIN  = 64 * 64;        // 4096 windows
static constexpr int VSTR  = 56;             // vT padded key stride

// map windowed token index tw -> unwindowed token index (shift+window bijection)
__device__ inline long win_to_tok(int tw)
{
    int win = tw / 49, n = tw % 49;
    int bb  = win >> 6, wi = win & 63;
    int wh  = wi >> 3, wwp = wi & 7;
    int hs  = wh * 7 + n / 7;
    int wsv = wwp * 7 + n % 7;
    int hh  = (hs + 3) % 56;          // un-shift
    int ww  = (wsv + 3) % 56;
    return (long)bb * L_ + hh * 56 + ww;
}

__device__ inline unsigned int pk2(float lo, float hi)
{
    unsigned short a = __builtin_bit_cast(unsigned short, (__bf16)lo);
    unsigned short b = __builtin_bit_cast(unsigned short, (__bf16)hi);
    return (unsigned int)a | ((unsigned int)b << 16);
}

// tanh-form GELU: ~8 VALU ops, |err| <= ~3e-3 (threshold is 0.11).
__device__ inline float gelu_f(float x)
{
    float u = 0.7978845608f * x * (1.f + 0.044715f * x * x);
    float e = __expf(2.f * fminf(u, 15.f));
    return x * e * __builtin_amdgcn_rcpf(e + 1.f);
}

__global__ void sentinel_kernel(float* o) { o[threadIdx.x] = 1e9f; }

// ---------------------------------------------------------------------------
__global__ void transpose_w(const float* __restrict__ w, bf16_t* __restrict__ wt,
                            int K, int N)
{
    int i = blockIdx.x * 256 + threadIdx.x;
    if (i >= K * N) return;
    int k = i / N, n = i % N;
    wt[(long)n * K + k] = __float2bfloat16(w[i]);
}

// zero vT pad keys 49..55 for all (win, d)
__global__ void zpad_kernel(bf16_t* __restrict__ vT)
{
    long i = (long)blockIdx.x * 256 + threadIdx.x;
    if (i >= (long)NWIN * 128 * 7) return;
    long row = i / 7;
    int  k   = 49 + (int)(i % 7);
    vT[row * VSTR + k] = __float2bfloat16(0.f);
}

// ---------------------------------------------------------------------------
// Fused LN1 + QKV projection, x read ONCE. (unchanged from R13, proven)
// ---------------------------------------------------------------------------
__global__ __launch_bounds__(256) void qkv_fused(const float* __restrict__ x,
                                                 const float* __restrict__ lng,
                                                 const float* __restrict__ lnb,
                                                 const bf16_t* __restrict__ Bt,
                                                 const float*  __restrict__ bias,
                                                 bf16_t* __restrict__ qk,
                                                 bf16_t* __restrict__ vT)
{
    __shared__ char xn[64 * 256];            // 16 KB
    int tid  = threadIdx.x;
    int wave = tid >> 6;
    int lane = tid & 63;
    int la = lane & 15, lb = lane >> 4;
    int m0 = blockIdx.x * 64;

    // ---- stage: LN1 of row (wave*16+la) -> LDS ----
    {
        int row = wave * 16 + la;
        long src = win_to_tok(m0 + row);
        const float* xr = x + src * C_;
        float vals[4][8];
        float sm = 0.f, qs = 0.f;
#pragma unroll
        for (int kt = 0; kt < 4; ++kt) {
            f32x4 u0 = *reinterpret_cast<const f32x4*>(xr + kt * 32 + lb * 8);
            f32x4 u1 = *reinterpret_cast<const f32x4*>(xr + kt * 32 + lb * 8 + 4);
#pragma unroll
            for (int j = 0; j < 4; ++j) { vals[kt][j] = u0[j]; vals[kt][4 + j] = u1[j]; }
#pragma unroll
            for (int j = 0; j < 8; ++j) { sm += vals[kt][j]; qs += vals[kt][j] * vals[kt][j]; }
        }
        sm += __shfl_xor(sm, 16); sm += __shfl_xor(sm, 32);
        qs += __shfl_xor(qs, 16); qs += __shfl_xor(qs, 32);
        float mean = sm * (1.f / 128.f);
        float rstd = rsqrtf(qs * (1.f / 128.f) - mean * mean + 1e-5f);
#pragma unroll
        for (int kt = 0; kt < 4; ++kt) {
            bf16x8 v8;
#pragma unroll
            for (int j = 0; j < 8; ++j) {
                int col = kt * 32 + lb * 8 + j;
                v8[j] = (__bf16)((vals[kt][j] - mean) * rstd * lng[col] + lnb[col]);
            }
            int colb = kt * 64 + lb * 16;
            *reinterpret_cast<bf16x8*>(xn + row * 256 + (colb ^ ((row & 7) << 4))) = v8;
        }
    }
    __syncthreads();

    // ---- compute: 64 rows x 96 cols per wave ----
    int c0 = wave * 96;
    f32x4 acc[4][6];
#pragma unroll
    for (int nt = 0; nt < 6; ++nt) {
        float bv = bias[c0 + nt * 16 + la];
#pragma unroll
        for (int s = 0; s < 4; ++s) acc[s][nt] = (f32x4){bv, bv, bv, bv};
    }

#pragma unroll
    for (int kt = 0; kt < 4; ++kt) {
        bf16x8 ar[4];
#pragma unroll
        for (int s = 0; s < 4; ++s) {
            int row = s * 16 + la;
            ar[s] = *reinterpret_cast<const bf16x8*>(
                xn + row * 256 + ((kt * 64 + lb * 16) ^ ((row & 7) << 4)));
        }
#pragma unroll
        for (int nt = 0; nt < 6; ++nt) {
            bf16x8 br = *reinterpret_cast<const bf16x8*>(
                Bt + (long)(c0 + nt * 16 + la) * 128 + kt * 32 + lb * 8);
#pragma unroll
            for (int s = 0; s < 4; ++s)
                acc[s][nt] = __builtin_amdgcn_mfma_f32_16x16x32_bf16(
                    ar[s], br, acc[s][nt], 0, 0, 0);
        }
    }

    // ---- epilogue ----
#pragma unroll
    for (int s = 0; s < 4; ++s) {
#pragma unroll
        for (int r = 0; r < 4; ++r) {
            int row = m0 + s * 16 + lb * 4 + r;
            int win = row / 49, key = row - win * 49;
#pragma unroll
            for (int nt = 0; nt < 6; ++nt) {
                int col = c0 + nt * 16 + la;
                float v = acc[s][nt][r];
                if (col < 256)
                    qk[(long)row * 256 + col] = __float2bfloat16(v);
                else
                    vT[((long)win * 128 + (col - 256)) * VSTR + key] = __float2bfloat16(v);
            }
        }
    }
}

// ---------------------------------------------------------------------------
// MFMA windowed attention + fused proj + window-reverse + x residual.
// One block per window, one wave per head.  y output is now bf16.
// ---------------------------------------------------------------------------
__global__ __launch_bounds__(256) void attn_mfma(const bf16_t* __restrict__ qk,
                                                 const bf16_t* __restrict__ vT,
                                                 const float*  __restrict__ rpb,
                                                 const bf16_t* __restrict__ projwt,
                                                 const float*  __restrict__ projb,
                                                 const float*  __restrict__ x,
                                                 bf16_t* __restrict__ y)
{
    int win  = blockIdx.x;
    int h    = threadIdx.x >> 6;
    int lane = threadIdx.x & 63;
    int la = lane & 15, lb = lane >> 4;

    __shared__ __bf16 attw[49][152];

    const bf16_t* qkw = qk + (long)win * 49 * 256;

    bf16x8 kf[4], qf[4];
#pragma unroll
    for (int t = 0; t < 4; ++t) {
        kf[t] = *reinterpret_cast<const bf16x8*>(qkw + (long)(t * 16 + la) * 256 + 128 + h * 32 + lb * 8);
        qf[t] = *reinterpret_cast<const bf16x8*>(qkw + (long)(t * 16 + la) * 256 +       h * 32 + lb * 8);
    }

    f32x4 S[4][4];
#pragma unroll
    for (int qt = 0; qt < 4; ++qt)
#pragma unroll
        for (int kt = 0; kt < 4; ++kt)
            S[qt][kt] = __builtin_amdgcn_mfma_f32_16x16x32_bf16(
                kf[kt], qf[qt], (f32x4){0.f, 0.f, 0.f, 0.f}, 0, 0, 0);

    const float scale = 0.17677669529663687f;   // 1/sqrt(32)
    int wi  = win & 63;
    int wh  = wi >> 3, wwp = wi & 7;
    bool edge = (wh == 7) || (wwp == 7);

    int i1[4], j1[4], r1[4], c1[4];
#pragma unroll
    for (int qt = 0; qt < 4; ++qt) {
        int q  = qt * 16 + la;
        int qc = q < 49 ? q : 48;
        i1[qt] = qc / 7; j1[qt] = qc - 7 * i1[qt];
        r1[qt] = (wh  < 7) ? 0 : ((i1[qt] < 4) ? 1 : 2);
        c1[qt] = (wwp < 7) ? 0 : ((j1[qt] < 4) ? 1 : 2);
    }

#pragma unroll
    for (int kt = 0; kt < 4; ++kt) {
#pragma unroll
        for (int r = 0; r < 4; ++r) {
            if (kt == 3 && r > 0) {
#pragma unroll
                for (int qt = 0; qt < 4; ++qt) S[qt][kt][r] = -1e30f;
                continue;
            }
            int key = kt * 16 + lb * 4 + r;
            int kc  = key < 49 ? key : 48;
            int i2  = kc / 7, j2 = kc - 7 * i2;
            int r2  = (wh  < 7) ? 0 : ((i2 < 4) ? 1 : 2);
            int c2  = (wwp < 7) ? 0 : ((j2 < 4) ? 1 : 2);
#pragma unroll
            for (int qt = 0; qt < 4; ++qt) {
                float bv  = rpb[(((i1[qt] - i2 + 6) * 13 + (j1[qt] - j2 + 6)) << 2) + h];
                float val = S[qt][kt][r] * scale + bv;
                if (edge && ((r1[qt] != r2) | (c1[qt] != c2))) val -= 100.f;
                if (kt == 3 && lb > 0) val = -1e30f;
                S[qt][kt][r] = val;
            }
        }
    }

    float inv[4];
#pragma unroll
    for (int qt = 0; qt < 4; ++qt) {
        float mx = -3e38f;
#pragma unroll
        for (int kt = 0; kt < 4; ++kt)
#pragma unroll
            for (int r = 0; r < 4; ++r) mx = fmaxf(mx, S[qt][kt][r]);
        mx = fmaxf(mx, __shfl_xor(mx, 16));
        mx = fmaxf(mx, __shfl_xor(mx, 32));
        float sm = 0.f;
#pragma unroll
        for (int kt = 0; kt < 4; ++kt)
#pragma unroll
            for (int r = 0; r < 4; ++r) {
                float e = __expf(S[qt][kt][r] - mx);
                S[qt][kt][r] = e;
                sm += e;
            }
        sm += __shfl_xor(sm, 16);
        sm += __shfl_xor(sm, 32);
        inv[qt] = 1.f / sm;
    }

    unsigned int w_[4][4][2];
#pragma unroll
    for (int qt = 0; qt < 4; ++qt)
#pragma unroll
        for (int t = 0; t < 4; ++t) {
            w_[qt][t][0] = pk2(S[qt][t][0], S[qt][t][1]);
            w_[qt][t][1] = pk2(S[qt][t][2], S[qt][t][3]);
        }

    int srcA = la + (((2 * lb)     & 3) << 4);
    int srcB = la + (((2 * lb + 1) & 3) << 4);
    bool hiT = (lb >> 1) & 1;

    f32x4 O[2][4];
#pragma unroll
    for (int dt = 0; dt < 2; ++dt)
#pragma unroll
        for (int qt = 0; qt < 4; ++qt) O[dt][qt] = (f32x4){0.f, 0.f, 0.f, 0.f};

    const bf16_t* vrow = vT + ((long)win * 128 + h * 32) * VSTR;
#pragma unroll
    for (int kk = 0; kk < 2; ++kk) {
        bf16x8 vf[2];
#pragma unroll
        for (int dt = 0; dt < 2; ++dt)
            vf[dt] = *reinterpret_cast<const bf16x8*>(
                vrow + (long)(dt * 16 + la) * VSTR + kk * 32 + lb * 8);
        int tl = kk * 2;
#pragma unroll
        for (int qt = 0; qt < 4; ++qt) {
            unsigned int a0 = __shfl(w_[qt][tl][0],     srcA);
            unsigned int b0 = __shfl(w_[qt][tl + 1][0], srcA);
            unsigned int a1 = __shfl(w_[qt][tl][1],     srcA);
            unsigned int b1 = __shfl(w_[qt][tl + 1][1], srcA);
            unsigned int a2 = __shfl(w_[qt][tl][0],     srcB);
            unsigned int b2 = __shfl(w_[qt][tl + 1][0], srcB);
            unsigned int a3 = __shfl(w_[qt][tl][1],     srcB);
            unsigned int b3 = __shfl(w_[qt][tl + 1][1], srcB);
            u32x4 uu = { hiT ? b0 : a0, hiT ? b1 : a1, hiT ? b2 : a2, hiT ? b3 : a3 };
            bf16x8 pf = __builtin_bit_cast(bf16x8, uu);
#pragma unroll
            for (int dt = 0; dt < 2; ++dt)
                O[dt][qt] = __builtin_amdgcn_mfma_f32_16x16x32_bf16(vf[dt], pf, O[dt][qt], 0, 0, 0);
        }
    }

    // ---- normalized O -> LDS (each wave owns cols h*32..h*32+31) ----
#pragma unroll
    for (int qt = 0; qt < 4; ++qt) {
        int q = qt * 16 + la;
        if (q < 49) {
            float iv = inv[qt];
#pragma unroll
            for (int dt = 0; dt < 2; ++dt) {
                unsigned int s0 = pk2(O[dt][qt][0] * iv, O[dt][qt][1] * iv);
                unsigned int s1 = pk2(O[dt][qt][2] * iv, O[dt][qt][3] * iv);
                uint2 st = {s0, s1};
                *reinterpret_cast<uint2*>(&attw[q][h * 32 + dt * 16 + lb * 4]) = st;
            }
        }
    }
    __syncthreads();

    // ---- proj: wave h computes C[q=0..63][n=h*32..h*32+31] ----
    int n0 = h * 32;
    f32x4 pacc[4][2];
#pragma unroll
    for (int nt = 0; nt < 2; ++nt) {
        float bv = projb[n0 + nt * 16 + la];
#pragma unroll
        for (int s = 0; s < 4; ++s) pacc[s][nt] = (f32x4){bv, bv, bv, bv};
    }
#pragma unroll
    for (int kt = 0; kt < 4; ++kt) {
        bf16x8 ar[4];
#pragma unroll
        for (int s = 0; s < 4; ++s)
            ar[s] = *reinterpret_cast<const bf16x8*>(&attw[s * 16 + la][kt * 32 + lb * 8]);
#pragma unroll
        for (int nt = 0; nt < 2; ++nt) {
            bf16x8 br = *reinterpret_cast<const bf16x8*>(
                projwt + (long)(n0 + nt * 16 + la) * 128 + kt * 32 + lb * 8);
#pragma unroll
            for (int s = 0; s < 4; ++s)
                pacc[s][nt] = __builtin_amdgcn_mfma_f32_16x16x32_bf16(
                    ar[s], br, pacc[s][nt], 0, 0, 0);
        }
    }

    // ---- epilogue: window-reverse + unshift + x residual -> bf16 y ----
#pragma unroll
    for (int s = 0; s < 4; ++s) {
#pragma unroll
        for (int r = 0; r < 4; ++r) {
            int q = s * 16 + lb * 4 + r;
            if (q < 49) {
                long to = win_to_tok(win * 49 + q);
#pragma unroll
                for (int nt = 0; nt < 2; ++nt) {
                    int col = n0 + nt * 16 + la;
                    y[to * C_ + col] =
                        __float2bfloat16(pacc[s][nt][r] + x[to * C_ + col]);
                }
            }
        }
    }
}

// ---------------------------------------------------------------------------
// Fused MLP v8: y is bf16; 512-thread blocks (8 waves, 256 rows) halve the
// per-block weight-staging traffic. Single 32 KB LDS buffer, stage ->
// barrier -> compute -> barrier per chunk. XOR-swizzled LDS rows.
// out (f32, d_out) written exactly once.
// ---------------------------------------------------------------------------
__global__ __launch_bounds__(512, 4) void mlp_fused(const bf16_t* __restrict__ y,
                                                    const float* __restrict__ g,
                                                    const float* __restrict__ b,
                                                    const bf16_t* __restrict__ w1t,
                                                    const float* __restrict__ b1,
                                                    const bf16_t* __restrict__ w2t,
                                                    const float* __restrict__ b2,
                                                    float* __restrict__ out)
{
    __shared__ uint4 ldsq[2048];             // 32 KB: [W1c 16KB | W2c 16KB]
    int tid  = threadIdx.x;
    int lane = tid & 63;
    int la = lane & 15, lb = lane >> 4;
    int m0 = (blockIdx.x * 8 + (tid >> 6)) * 32;

    auto stage = [&](int c) {
        char* d1 = (char*)&ldsq[0];
        const char* s1 = (const char*)w1t + (size_t)c * 16384;
#pragma unroll
        for (int i = 0; i < 2; ++i) {
            int idx = i * 512 + tid;             // 0..1023, 16B units
            int row = idx >> 4, colb = (idx & 15) * 16;
            uint4 v = *reinterpret_cast<const uint4*>(s1 + idx * 16);
            *reinterpret_cast<uint4*>(d1 + row * 256 + (colb ^ ((row & 7) << 4))) = v;
        }
        char* d2 = (char*)&ldsq[1024];
        const char* s2 = (const char*)w2t + (size_t)c * 128;
#pragma unroll
        for (int i = 0; i < 2; ++i) {
            int idx = i * 512 + tid;             // 0..1023
            int row = idx >> 3, colb = (idx & 7) * 16;
            uint4 v = *reinterpret_cast<const uint4*>(s2 + (size_t)row * 1024 + colb);
            *reinterpret_cast<uint4*>(d2 + row * 128 + (colb ^ ((row & 7) << 4))) = v;
        }
    };

    // ---- LN2 -> fragments for 2 row-subtiles (m = s*16+la, k = kt*32+lb*8+j)
    bf16x8 af[2][4];
#pragma unroll
    for (int s = 0; s < 2; ++s) {
        const bf16_t* yr = y + (long)(m0 + s * 16 + la) * C_;
        float vals[4][8];
        float sm = 0.f, qs = 0.f;
#pragma unroll
        for (int kt = 0; kt < 4; ++kt) {
            bf16x8 v8 = *reinterpret_cast<const bf16x8*>(yr + kt * 32 + lb * 8);
#pragma unroll
            for (int j = 0; j < 8; ++j) {
                float v = (float)v8[j];
                vals[kt][j] = v; sm += v; qs += v * v;
            }
        }
        sm += __shfl_xor(sm, 16); sm += __shfl_xor(sm, 32);
        qs += __shfl_xor(qs, 16); qs += __shfl_xor(qs, 32);
        float mean = sm * (1.f / 128.f);
        float rstd = rsqrtf(qs * (1.f / 128.f) - mean * mean + 1e-5f);
#pragma unroll
        for (int kt = 0; kt < 4; ++kt)
#pragma unroll
            for (int j = 0; j < 8; ++j) {
                int col = kt * 32 + lb * 8 + j;
                af[s][kt][j] = (__bf16)((vals[kt][j] - mean) * rstd * g[col] + b[col]);
            }
    }

    // ---- out^T accumulators: acc[s][nt2]: out[m=s*16+la][n2=nt2*16+lb*4+r]
    f32x4 acc[2][8];
#pragma unroll
    for (int nt2 = 0; nt2 < 8; ++nt2) {
        f32x4 bv = *reinterpret_cast<const f32x4*>(b2 + nt2 * 16 + lb * 4);
#pragma unroll
        for (int s = 0; s < 2; ++s) acc[s][nt2] = bv;
    }

    int srcA = la + (((2 * lb)     & 3) << 4);
    int srcB = la + (((2 * lb + 1) & 3) << 4);
    bool hiT = (lb >> 1) & 1;

    for (int c = 0; c < 8; ++c) {
        stage(c);
        __syncthreads();

        const char* L1 = (const char*)&ldsq[0];
        const char* L2 = (const char*)&ldsq[1024];

        // ---- fc1 chunk TRANSPOSED from LDS: hT[n1][m] ----
        f32x4 hacc[2][4];
#pragma unroll
        for (int nt = 0; nt < 4; ++nt) {
            f32x4 bv = *reinterpret_cast<const f32x4*>(b1 + c * 64 + nt * 16 + lb * 4);
#pragma unroll
            for (int s = 0; s < 2; ++s) hacc[s][nt] = bv;
        }
#pragma unroll
        for (int kt = 0; kt < 4; ++kt)
#pragma unroll
            for (int nt = 0; nt < 4; ++nt) {
                int row = nt * 16 + la;
                bf16x8 w1f = *reinterpret_cast<const bf16x8*>(
                    L1 + row * 256 + ((kt * 64 + lb * 16) ^ ((row & 7) << 4)));
#pragma unroll
                for (int s = 0; s < 2; ++s)
                    hacc[s][nt] = __builtin_amdgcn_mfma_f32_16x16x32_bf16(
                        w1f, af[s][kt], hacc[s][nt], 0, 0, 0);
            }
        // ---- fast GELU + pack ----
        unsigned int wpk[2][4][2];
#pragma unroll
        for (int s = 0; s < 2; ++s)
#pragma unroll
            for (int t = 0; t < 4; ++t) {
                f32x4 hv = hacc[s][t];
#pragma unroll
                for (int r = 0; r < 4; ++r) hv[r] = gelu_f(hv[r]);
                wpk[s][t][0] = pk2(hv[0], hv[1]);
                wpk[s][t][1] = pk2(hv[2], hv[3]);
            }
        // ---- fc2 chunk ----
#pragma unroll
        for (int kk = 0; kk < 2; ++kk) {
            int tl = kk * 2;
#pragma unroll
            for (int s = 0; s < 2; ++s) {
                unsigned int a0 = __shfl(wpk[s][tl][0],     srcA);
                unsigned int b0 = __shfl(wpk[s][tl + 1][0], srcA);
                unsigned int a1 = __shfl(wpk[s][tl][1],     srcA);
                unsigned int b1v = __shfl(wpk[s][tl + 1][1], srcA);
                unsigned int a2 = __shfl(wpk[s][tl][0],     srcB);
                unsigned int b2v = __shfl(wpk[s][tl + 1][0], srcB);
                unsigned int a3 = __shfl(wpk[s][tl][1],     srcB);
                unsigned int b3v = __shfl(wpk[s][tl + 1][1], srcB);
                u32x4 uu = { hiT ? b0 : a0, hiT ? b1v : a1, hiT ? b2v : a2, hiT ? b3v : a3 };
                bf16x8 pf = __builtin_bit_cast(bf16x8, uu);
#pragma unroll
                for (int nt2 = 0; nt2 < 8; ++nt2) {
                    int row2 = nt2 * 16 + la;
                    bf16x8 w2f = *reinterpret_cast<const bf16x8*>(
                        L2 + row2 * 128 + ((kk * 64 + lb * 16) ^ ((row2 & 7) << 4)));
                    acc[s][nt2] = __builtin_amdgcn_mfma_f32_16x16x32_bf16(
                        w2f, pf, acc[s][nt2], 0, 0, 0);
                }
            }
        }
        __syncthreads();   // all waves done reading before next stage
    }

    // ---- epilogue: + y residual (bf16) -> f32 out ----
#pragma unroll
    for (int s = 0; s < 2; ++s) {
        long m = m0 + s * 16 + la;
        const bf16_t* yrow = y + m * C_;
        float* orow = out + m * C_;
#pragma unroll
        for (int nt2 = 0; nt2 < 8; ++nt2) {
            int n2 = nt2 * 16 + lb * 4;
            bf16x4 rb = *reinterpret_cast<const bf16x4*>(yrow + n2);
            f32x4 val = acc[s][nt2];
#pragma unroll
            for (int r = 0; r < 4; ++r) val[r] += (float)rb[r];
            *reinterpret_cast<f32x4*>(orow + n2) = val;
        }
    }
}

// ---------------------------------------------------------------------------
extern "C" void kernel_launch(void* const* d_in, const int* in_sizes, int n_in,
                              void* d_out, int out_size, void* d_ws, size_t ws_size,
                              hipStream_t stream)
{
    (void)in_sizes; (void)n_in; (void)out_size;

    const float* x      = (const float*)d_in[0];
    const float* n1g    = (const float*)d_in[1];
    const float* n1b    = (const float*)d_in[2];
    const float* qkv_w  = (const float*)d_in[3];
    const float* qkv_b  = (const float*)d_in[4];
    const float* proj_w = (const float*)d_in[5];
    const float* proj_b = (const float*)d_in[6];
    const float* rpb    = (const float*)d_in[7];
    const float* n2g    = (const float*)d_in[8];
    const float* n2b    = (const float*)d_in[9];
    const float* fc1_w  = (const float*)d_in[10];
    const float* fc1_b  = (const float*)d_in[11];
    const float* fc2_w  = (const float*)d_in[12];
    const float* fc2_b  = (const float*)d_in[13];

    char* ws = (char*)d_ws;

    const size_t qk_sz = (size_t)M_ * 256 * 2;               // 102,760,448
    const size_t vt_sz = (size_t)NWIN * 128 * VSTR * 2;      //  58,720,256
    const size_t yb_sz = (size_t)M_ * 128 * 2;               //  51,380,224 (bf16 y)
    const size_t w_off = qk_sz + vt_sz + yb_sz;
    const size_t w_sz  = (size_t)(128 * 384 + 128 * 128 + 128 * 512 + 512 * 128) * 2;
    const size_t need  = w_off + w_sz;                       // ~213.6 MB (proven fit)

    if (need > ws_size) {
        sentinel_kernel<<<1, 256, 0, stream>>>((float*)d_out);
        return;
    }

    bf16_t* qkb  = (bf16_t*)ws;
    bf16_t* vT   = (bf16_t*)(ws + qk_sz);
    bf16_t* yb   = (bf16_t*)(ws + qk_sz + vt_sz);
    bf16_t* qkv_wt  = (bf16_t*)(ws + w_off);
    bf16_t* proj_wt = qkv_wt + 128 * 384;
    bf16_t* fc1_wt  = proj_wt + 128 * 128;
    bf16_t* fc2_wt  = fc1_wt + 128 * 512;

    transpose_w<<<(128 * 384 + 255) / 256, 256, 0, stream>>>(qkv_w, qkv_wt, 128, 384);
    transpose_w<<<(128 * 128 + 255) / 256, 256, 0, stream>>>(proj_w, proj_wt, 128, 128);
    transpose_w<<<(128 * 512 + 255) / 256, 256, 0, stream>>>(fc1_w, fc1_wt, 128, 512);
    transpose_w<<<(512 * 128 + 255) / 256, 256, 0, stream>>>(fc2_w, fc2_wt, 512, 128);

    // zero vT pad keys (NaN safety for PV fragments)
    zpad_kernel<<<(NWIN * 128 * 7 + 255) / 256, 256, 0, stream>>>(vT);
    // LN1 + QKV projection, x read once
    qkv_fused<<<M_ / 64, 256, 0, stream>>>(x, n1g, n1b, qkv_wt, qkv_b, qkb, vT);
    // MFMA attention + fused proj + window-reverse + x residual -> bf16 y
    attn_mfma<<<NWIN, 256, 0, stream>>>(qkb, vT, rpb, proj_wt, proj_b, x, yb);
    // fused LN2 + fc1 + GELU + fc2 + residual -> f32 d_out
    mlp_fused<<<M_ / 256, 512, 0, stream>>>(
        yb, n2g, n2b, fc1_wt, fc1_b, fc2_wt, fc2_b, (float*)d_out);
}

// Round 15
// 383.028 us; speedup vs baseline: 2.3314x; 1.2349x over previous
//
#include <hip/hip_runtime.h>
#include <hip/hip_bf16.h>
#include <math.h>

typedef __bf16 bf16x8 __attribute__((ext_vector_type(8)));
typedef __bf16 bf16x4 __attribute__((ext_vector_type(4)));
typedef float  f32x4  __attribute__((ext_vector_type(4)));
typedef unsigned int u32x4 __attribute__((ext_vector_type(4)));
typedef __hip_bfloat16 bf16_t;

static constexpr int C_    = 128;
static constexpr int L_    = 56 * 56;        // tokens per image
static constexpr int M_    = 64 * L_;        // 200704 total tokens
static constexpr int NWIN  = 64 * 64;        // 4096 windows

// map windowed token index tw -> unwindowed token index (shift+window bijection)
__device__ inline long win_to_tok(int tw)
{
    int win = tw / 49, n = tw % 49;
    int bb  = win >> 6, wi = win & 63;
    int wh  = wi >> 3, wwp = wi & 7;
    int hs  = wh * 7 + n / 7;
    int wsv = wwp * 7 + n % 7;
    int hh  = (hs + 3) % 56;          // un-shift
    int ww  = (wsv + 3) % 56;
    return (long)bb * L_ + hh * 56 + ww;
}

__device__ inline unsigned int pk2(float lo, float hi)
{
    unsigned short a = __builtin_bit_cast(unsigned short, (__bf16)lo);
    unsigned short b = __builtin_bit_cast(unsigned short, (__bf16)hi);
    return (unsigned int)a | ((unsigned int)b << 16);
}

// tanh-form GELU: ~8 VALU ops, |err| <= ~3e-3 (threshold is 0.11).
__device__ inline float gelu_f(float x)
{
    float u = 0.7978845608f * x * (1.f + 0.044715f * x * x);
    float e = __expf(2.f * fminf(u, 15.f));
    return x * e * __builtin_amdgcn_rcpf(e + 1.f);
}

__global__ void sentinel_kernel(float* o) { o[threadIdx.x] = 1e9f; }

// ---------------------------------------------------------------------------
__global__ void transpose_w(const float* __restrict__ w, bf16_t* __restrict__ wt,
                            int K, int N)
{
    int i = blockIdx.x * 256 + threadIdx.x;
    if (i >= K * N) return;
    int k = i / N, n = i % N;
    wt[(long)n * K + k] = __float2bfloat16(w[i]);
}

// ---------------------------------------------------------------------------
// Fully fused Swin attention half: LN1 + qkv + windowed attention + proj +
// window-reverse + x residual, one block per window (4 waves = 4 heads).
// LDS: xn[64][256B] (aliased by attw[49][152] after phase 2) |
//      qk[64][512B] XOR-swizzled | vT[128][56] bf16 (pads zeroed).
// ---------------------------------------------------------------------------
__global__ __launch_bounds__(256) void swin_fused(const float* __restrict__ x,
                                                  const float* __restrict__ lng,
                                                  const float* __restrict__ lnb,
                                                  const bf16_t* __restrict__ qkvwt,
                                                  const float*  __restrict__ qkvb,
                                                  const float*  __restrict__ rpb,
                                                  const bf16_t* __restrict__ projwt,
                                                  const float*  __restrict__ projb,
                                                  bf16_t* __restrict__ y)
{
    __shared__ char smem[16384 + 32768 + 14336];   // 63.5 KB
    char*   xnb = smem;                    // phase 1-2: LN1'd x; phase 3+: attw
    char*   qkb = smem + 16384;            // [64 rows][512 B], swizzled
    __bf16* vtb = (__bf16*)(smem + 49152); // [128][56]

    int win  = blockIdx.x;
    int tid  = threadIdx.x;
    int wave = tid >> 6;
    int lane = tid & 63;
    int la = lane & 15, lb = lane >> 4;

    // zero vT pad keys 49..55 (NaN safety: P[pad]=0 x V[pad] must be 0)
    for (int i = tid; i < 128 * 7; i += 256)
        vtb[(i / 7) * 56 + 49 + i % 7] = (__bf16)0.f;

    // ---- phase 1: LN1 of window tokens -> xn ----
    {
        int row = wave * 16 + la;
        int tw  = win * 49 + row;
        if (tw > M_ - 1) tw = M_ - 1;      // rows >=49 duplicate data, discarded
        long src = win_to_tok(tw);
        const float* xr = x + src * C_;
        float vals[4][8];
        float sm = 0.f, qs = 0.f;
#pragma unroll
        for (int kt = 0; kt < 4; ++kt) {
            f32x4 u0 = *reinterpret_cast<const f32x4*>(xr + kt * 32 + lb * 8);
            f32x4 u1 = *reinterpret_cast<const f32x4*>(xr + kt * 32 + lb * 8 + 4);
#pragma unroll
            for (int j = 0; j < 4; ++j) { vals[kt][j] = u0[j]; vals[kt][4 + j] = u1[j]; }
#pragma unroll
            for (int j = 0; j < 8; ++j) { sm += vals[kt][j]; qs += vals[kt][j] * vals[kt][j]; }
        }
        sm += __shfl_xor(sm, 16); sm += __shfl_xor(sm, 32);
        qs += __shfl_xor(qs, 16); qs += __shfl_xor(qs, 32);
        float mean = sm * (1.f / 128.f);
        float rstd = rsqrtf(qs * (1.f / 128.f) - mean * mean + 1e-5f);
#pragma unroll
        for (int kt = 0; kt < 4; ++kt) {
            bf16x8 v8;
#pragma unroll
            for (int j = 0; j < 8; ++j) {
                int col = kt * 32 + lb * 8 + j;
                v8[j] = (__bf16)((vals[kt][j] - mean) * rstd * lng[col] + lnb[col]);
            }
            int colb = kt * 64 + lb * 16;
            *reinterpret_cast<bf16x8*>(xnb + row * 256 + (colb ^ ((row & 7) << 4))) = v8;
        }
    }
    __syncthreads();

    // ---- phase 2: qkv, wave = 64 rows x 96 cols; outputs -> LDS ----
    {
        int c0 = wave * 96;
        f32x4 acc[4][6];
#pragma unroll
        for (int nt = 0; nt < 6; ++nt) {
            float bv = qkvb[c0 + nt * 16 + la];
#pragma unroll
            for (int s = 0; s < 4; ++s) acc[s][nt] = (f32x4){bv, bv, bv, bv};
        }
#pragma unroll
        for (int kt = 0; kt < 4; ++kt) {
            bf16x8 ar[4];
#pragma unroll
            for (int s = 0; s < 4; ++s) {
                int row = s * 16 + la;
                ar[s] = *reinterpret_cast<const bf16x8*>(
                    xnb + row * 256 + ((kt * 64 + lb * 16) ^ ((row & 7) << 4)));
            }
#pragma unroll
            for (int nt = 0; nt < 6; ++nt) {
                bf16x8 br = *reinterpret_cast<const bf16x8*>(
                    qkvwt + (long)(c0 + nt * 16 + la) * 128 + kt * 32 + lb * 8);
#pragma unroll
                for (int s = 0; s < 4; ++s)
                    acc[s][nt] = __builtin_amdgcn_mfma_f32_16x16x32_bf16(
                        ar[s], br, acc[s][nt], 0, 0, 0);
            }
        }
        // epilogue -> LDS (q,k swizzled rows; v transposed, key<49 only)
#pragma unroll
        for (int s = 0; s < 4; ++s) {
#pragma unroll
            for (int r = 0; r < 4; ++r) {
                int row = s * 16 + lb * 4 + r;     // window-local token = key
#pragma unroll
                for (int nt = 0; nt < 6; ++nt) {
                    int col = c0 + nt * 16 + la;
                    float v = acc[s][nt][r];
                    if (col < 256) {
                        *reinterpret_cast<__bf16*>(
                            qkb + row * 512 + ((col * 2) ^ ((row & 7) << 4))) = (__bf16)v;
                    } else if (row < 49) {
                        vtb[(col - 256) * 56 + row] = (__bf16)v;
                    }
                }
            }
        }
    }
    __syncthreads();

    // ---- phase 3: attention (wave = head h) ----
    int h = wave;
    bf16x8 kf[4], qf[4];
#pragma unroll
    for (int t = 0; t < 4; ++t) {
        int row = t * 16 + la;
        kf[t] = *reinterpret_cast<const bf16x8*>(
            qkb + row * 512 + ((256 + h * 64 + lb * 16) ^ ((row & 7) << 4)));
        qf[t] = *reinterpret_cast<const bf16x8*>(
            qkb + row * 512 + ((      h * 64 + lb * 16) ^ ((row & 7) << 4)));
    }

    f32x4 S[4][4];
#pragma unroll
    for (int qt = 0; qt < 4; ++qt)
#pragma unroll
        for (int kt = 0; kt < 4; ++kt)
            S[qt][kt] = __builtin_amdgcn_mfma_f32_16x16x32_bf16(
                kf[kt], qf[qt], (f32x4){0.f, 0.f, 0.f, 0.f}, 0, 0, 0);

    const float scale = 0.17677669529663687f;   // 1/sqrt(32)
    int wi  = win & 63;
    int wh  = wi >> 3, wwp = wi & 7;
    bool edge = (wh == 7) || (wwp == 7);

    int i1[4], j1[4], r1[4], c1[4];
#pragma unroll
    for (int qt = 0; qt < 4; ++qt) {
        int q  = qt * 16 + la;
        int qc = q < 49 ? q : 48;
        i1[qt] = qc / 7; j1[qt] = qc - 7 * i1[qt];
        r1[qt] = (wh  < 7) ? 0 : ((i1[qt] < 4) ? 1 : 2);
        c1[qt] = (wwp < 7) ? 0 : ((j1[qt] < 4) ? 1 : 2);
    }

#pragma unroll
    for (int kt = 0; kt < 4; ++kt) {
#pragma unroll
        for (int r = 0; r < 4; ++r) {
            if (kt == 3 && r > 0) {
#pragma unroll
                for (int qt = 0; qt < 4; ++qt) S[qt][kt][r] = -1e30f;
                continue;
            }
            int key = kt * 16 + lb * 4 + r;
            int kc  = key < 49 ? key : 48;
            int i2  = kc / 7, j2 = kc - 7 * i2;
            int r2  = (wh  < 7) ? 0 : ((i2 < 4) ? 1 : 2);
            int c2  = (wwp < 7) ? 0 : ((j2 < 4) ? 1 : 2);
#pragma unroll
            for (int qt = 0; qt < 4; ++qt) {
                float bv  = rpb[(((i1[qt] - i2 + 6) * 13 + (j1[qt] - j2 + 6)) << 2) + h];
                float val = S[qt][kt][r] * scale + bv;
                if (edge && ((r1[qt] != r2) | (c1[qt] != c2))) val -= 100.f;
                if (kt == 3 && lb > 0) val = -1e30f;
                S[qt][kt][r] = val;
            }
        }
    }

    float inv[4];
#pragma unroll
    for (int qt = 0; qt < 4; ++qt) {
        float mx = -3e38f;
#pragma unroll
        for (int kt = 0; kt < 4; ++kt)
#pragma unroll
            for (int r = 0; r < 4; ++r) mx = fmaxf(mx, S[qt][kt][r]);
        mx = fmaxf(mx, __shfl_xor(mx, 16));
        mx = fmaxf(mx, __shfl_xor(mx, 32));
        float sm = 0.f;
#pragma unroll
        for (int kt = 0; kt < 4; ++kt)
#pragma unroll
            for (int r = 0; r < 4; ++r) {
                float e = __expf(S[qt][kt][r] - mx);
                S[qt][kt][r] = e;
                sm += e;
            }
        sm += __shfl_xor(sm, 16);
        sm += __shfl_xor(sm, 32);
        inv[qt] = 1.f / sm;
    }

    unsigned int w_[4][4][2];
#pragma unroll
    for (int qt = 0; qt < 4; ++qt)
#pragma unroll
        for (int t = 0; t < 4; ++t) {
            w_[qt][t][0] = pk2(S[qt][t][0], S[qt][t][1]);
            w_[qt][t][1] = pk2(S[qt][t][2], S[qt][t][3]);
        }

    int srcA = la + (((2 * lb)     & 3) << 4);
    int srcB = la + (((2 * lb + 1) & 3) << 4);
    bool hiT = (lb >> 1) & 1;

    f32x4 O[2][4];
#pragma unroll
    for (int dt = 0; dt < 2; ++dt)
#pragma unroll
        for (int qt = 0; qt < 4; ++qt) O[dt][qt] = (f32x4){0.f, 0.f, 0.f, 0.f};

#pragma unroll
    for (int kk = 0; kk < 2; ++kk) {
        bf16x8 vf[2];
#pragma unroll
        for (int dt = 0; dt < 2; ++dt)
            vf[dt] = *reinterpret_cast<const bf16x8*>(
                vtb + (h * 32 + dt * 16 + la) * 56 + kk * 32 + lb * 8);
        int tl = kk * 2;
#pragma unroll
        for (int qt = 0; qt < 4; ++qt) {
            unsigned int a0 = __shfl(w_[qt][tl][0],     srcA);
            unsigned int b0 = __shfl(w_[qt][tl + 1][0], srcA);
            unsigned int a1 = __shfl(w_[qt][tl][1],     srcA);
            unsigned int b1 = __shfl(w_[qt][tl + 1][1], srcA);
            unsigned int a2 = __shfl(w_[qt][tl][0],     srcB);
            unsigned int b2 = __shfl(w_[qt][tl + 1][0], srcB);
            unsigned int a3 = __shfl(w_[qt][tl][1],     srcB);
            unsigned int b3 = __shfl(w_[qt][tl + 1][1], srcB);
            u32x4 uu = { hiT ? b0 : a0, hiT ? b1 : a1, hiT ? b2 : a2, hiT ? b3 : a3 };
            bf16x8 pf = __builtin_bit_cast(bf16x8, uu);
#pragma unroll
            for (int dt = 0; dt < 2; ++dt)
                O[dt][qt] = __builtin_amdgcn_mfma_f32_16x16x32_bf16(vf[dt], pf, O[dt][qt], 0, 0, 0);
        }
    }

    // ---- normalized O -> attw (aliases xn; xn dead since phase-2 barrier) ----
    __bf16 (*attw)[152] = (__bf16(*)[152])xnb;
#pragma unroll
    for (int qt = 0; qt < 4; ++qt) {
        int q = qt * 16 + la;
        if (q < 49) {
            float iv = inv[qt];
#pragma unroll
            for (int dt = 0; dt < 2; ++dt) {
                unsigned int s0 = pk2(O[dt][qt][0] * iv, O[dt][qt][1] * iv);
                unsigned int s1 = pk2(O[dt][qt][2] * iv, O[dt][qt][3] * iv);
                uint2 st = {s0, s1};
                *reinterpret_cast<uint2*>(&attw[q][h * 32 + dt * 16 + lb * 4]) = st;
            }
        }
    }
    __syncthreads();

    // ---- phase 4: proj, wave h = cols h*32..h*32+31 ----
    int n0 = h * 32;
    f32x4 pacc[4][2];
#pragma unroll
    for (int nt = 0; nt < 2; ++nt) {
        float bv = projb[n0 + nt * 16 + la];
#pragma unroll
        for (int s = 0; s < 4; ++s) pacc[s][nt] = (f32x4){bv, bv, bv, bv};
    }
#pragma unroll
    for (int kt = 0; kt < 4; ++kt) {
        bf16x8 ar[4];
#pragma unroll
        for (int s = 0; s < 4; ++s)
            ar[s] = *reinterpret_cast<const bf16x8*>(&attw[s * 16 + la][kt * 32 + lb * 8]);
#pragma unroll
        for (int nt = 0; nt < 2; ++nt) {
            bf16x8 br = *reinterpret_cast<const bf16x8*>(
                projwt + (long)(n0 + nt * 16 + la) * 128 + kt * 32 + lb * 8);
#pragma unroll
            for (int s = 0; s < 4; ++s)
                pacc[s][nt] = __builtin_amdgcn_mfma_f32_16x16x32_bf16(
                    ar[s], br, pacc[s][nt], 0, 0, 0);
        }
    }

    // ---- epilogue: window-reverse + unshift + x residual -> bf16 y ----
#pragma unroll
    for (int s = 0; s < 4; ++s) {
#pragma unroll
        for (int r = 0; r < 4; ++r) {
            int q = s * 16 + lb * 4 + r;
            if (q < 49) {
                long to = win_to_tok(win * 49 + q);
#pragma unroll
                for (int nt = 0; nt < 2; ++nt) {
                    int col = n0 + nt * 16 + la;
                    y[to * C_ + col] =
                        __float2bfloat16(pacc[s][nt][r] + x[to * C_ + col]);
                }
            }
        }
    }
}

// ---------------------------------------------------------------------------
// Fused MLP v8 (unchanged from R14): bf16 y, 512-thread blocks, single
// 32 KB LDS weight buffer, XOR-swizzled rows. out (f32) written once.
// ---------------------------------------------------------------------------
__global__ __launch_bounds__(512, 4) void mlp_fused(const bf16_t* __restrict__ y,
                                                    const float* __restrict__ g,
                                                    const float* __restrict__ b,
                                                    const bf16_t* __restrict__ w1t,
                                                    const float* __restrict__ b1,
                                                    const bf16_t* __restrict__ w2t,
                                                    const float* __restrict__ b2,
                                                    float* __restrict__ out)
{
    __shared__ uint4 ldsq[2048];             // 32 KB: [W1c 16KB | W2c 16KB]
    int tid  = threadIdx.x;
    int lane = tid & 63;
    int la = lane & 15, lb = lane >> 4;
    int m0 = (blockIdx.x * 8 + (tid >> 6)) * 32;

    auto stage = [&](int c) {
        char* d1 = (char*)&ldsq[0];
        const char* s1 = (const char*)w1t + (size_t)c * 16384;
#pragma unroll
        for (int i = 0; i < 2; ++i) {
            int idx = i * 512 + tid;             // 0..1023, 16B units
            int row = idx >> 4, colb = (idx & 15) * 16;
            uint4 v = *reinterpret_cast<const uint4*>(s1 + idx * 16);
            *reinterpret_cast<uint4*>(d1 + row * 256 + (colb ^ ((row & 7) << 4))) = v;
        }
        char* d2 = (char*)&ldsq[1024];
        const char* s2 = (const char*)w2t + (size_t)c * 128;
#pragma unroll
        for (int i = 0; i < 2; ++i) {
            int idx = i * 512 + tid;             // 0..1023
            int row = idx >> 3, colb = (idx & 7) * 16;
            uint4 v = *reinterpret_cast<const uint4*>(s2 + (size_t)row * 1024 + colb);
            *reinterpret_cast<uint4*>(d2 + row * 128 + (colb ^ ((row & 7) << 4))) = v;
        }
    };

    // ---- LN2 -> fragments for 2 row-subtiles ----
    bf16x8 af[2][4];
#pragma unroll
    for (int s = 0; s < 2; ++s) {
        const bf16_t* yr = y + (long)(m0 + s * 16 + la) * C_;
        float vals[4][8];
        float sm = 0.f, qs = 0.f;
#pragma unroll
        for (int kt = 0; kt < 4; ++kt) {
            bf16x8 v8 = *reinterpret_cast<const bf16x8*>(yr + kt * 32 + lb * 8);
#pragma unroll
            for (int j = 0; j < 8; ++j) {
                float v = (float)v8[j];
                vals[kt][j] = v; sm += v; qs += v * v;
            }
        }
        sm += __shfl_xor(sm, 16); sm += __shfl_xor(sm, 32);
        qs += __shfl_xor(qs, 16); qs += __shfl_xor(qs, 32);
        float mean = sm * (1.f / 128.f);
        float rstd = rsqrtf(qs * (1.f / 128.f) - mean * mean + 1e-5f);
#pragma unroll
        for (int kt = 0; kt < 4; ++kt)
#pragma unroll
            for (int j = 0; j < 8; ++j) {
                int col = kt * 32 + lb * 8 + j;
                af[s][kt][j] = (__bf16)((vals[kt][j] - mean) * rstd * g[col] + b[col]);
            }
    }

    f32x4 acc[2][8];
#pragma unroll
    for (int nt2 = 0; nt2 < 8; ++nt2) {
        f32x4 bv = *reinterpret_cast<const f32x4*>(b2 + nt2 * 16 + lb * 4);
#pragma unroll
        for (int s = 0; s < 2; ++s) acc[s][nt2] = bv;
    }

    int srcA = la + (((2 * lb)     & 3) << 4);
    int srcB = la + (((2 * lb + 1) & 3) << 4);
    bool hiT = (lb >> 1) & 1;

    for (int c = 0; c < 8; ++c) {
        stage(c);
        __syncthreads();

        const char* L1 = (const char*)&ldsq[0];
        const char* L2 = (const char*)&ldsq[1024];

        f32x4 hacc[2][4];
#pragma unroll
        for (int nt = 0; nt < 4; ++nt) {
            f32x4 bv = *reinterpret_cast<const f32x4*>(b1 + c * 64 + nt * 16 + lb * 4);
#pragma unroll
            for (int s = 0; s < 2; ++s) hacc[s][nt] = bv;
        }
#pragma unroll
        for (int kt = 0; kt < 4; ++kt)
#pragma unroll
            for (int nt = 0; nt < 4; ++nt) {
                int row = nt * 16 + la;
                bf16x8 w1f = *reinterpret_cast<const bf16x8*>(
                    L1 + row * 256 + ((kt * 64 + lb * 16) ^ ((row & 7) << 4)));
#pragma unroll
                for (int s = 0; s < 2; ++s)
                    hacc[s][nt] = __builtin_amdgcn_mfma_f32_16x16x32_bf16(
                        w1f, af[s][kt], hacc[s][nt], 0, 0, 0);
            }
        unsigned int wpk[2][4][2];
#pragma unroll
        for (int s = 0; s < 2; ++s)
#pragma unroll
            for (int t = 0; t < 4; ++t) {
                f32x4 hv = hacc[s][t];
#pragma unroll
                for (int r = 0; r < 4; ++r) hv[r] = gelu_f(hv[r]);
                wpk[s][t][0] = pk2(hv[0], hv[1]);
                wpk[s][t][1] = pk2(hv[2], hv[3]);
            }
#pragma unroll
        for (int kk = 0; kk < 2; ++kk) {
            int tl = kk * 2;
#pragma unroll
            for (int s = 0; s < 2; ++s) {
                unsigned int a0 = __shfl(wpk[s][tl][0],     srcA);
                unsigned int b0 = __shfl(wpk[s][tl + 1][0], srcA);
                unsigned int a1 = __shfl(wpk[s][tl][1],     srcA);
                unsigned int b1v = __shfl(wpk[s][tl + 1][1], srcA);
                unsigned int a2 = __shfl(wpk[s][tl][0],     srcB);
                unsigned int b2v = __shfl(wpk[s][tl + 1][0], srcB);
                unsigned int a3 = __shfl(wpk[s][tl][1],     srcB);
                unsigned int b3v = __shfl(wpk[s][tl + 1][1], srcB);
                u32x4 uu = { hiT ? b0 : a0, hiT ? b1v : a1, hiT ? b2v : a2, hiT ? b3v : a3 };
                bf16x8 pf = __builtin_bit_cast(bf16x8, uu);
#pragma unroll
                for (int nt2 = 0; nt2 < 8; ++nt2) {
                    int row2 = nt2 * 16 + la;
                    bf16x8 w2f = *reinterpret_cast<const bf16x8*>(
                        L2 + row2 * 128 + ((kk * 64 + lb * 16) ^ ((row2 & 7) << 4)));
                    acc[s][nt2] = __builtin_amdgcn_mfma_f32_16x16x32_bf16(
                        w2f, pf, acc[s][nt2], 0, 0, 0);
                }
            }
        }
        __syncthreads();
    }

    // ---- epilogue: + y residual (bf16) -> f32 out ----
#pragma unroll
    for (int s = 0; s < 2; ++s) {
        long m = m0 + s * 16 + la;
        const bf16_t* yrow = y + m * C_;
        float* orow = out + m * C_;
#pragma unroll
        for (int nt2 = 0; nt2 < 8; ++nt2) {
            int n2 = nt2 * 16 + lb * 4;
            bf16x4 rb = *reinterpret_cast<const bf16x4*>(yrow + n2);
            f32x4 val = acc[s][nt2];
#pragma unroll
            for (int r = 0; r < 4; ++r) val[r] += (float)rb[r];
            *reinterpret_cast<f32x4*>(orow + n2) = val;
        }
    }
}

// ---------------------------------------------------------------------------
extern "C" void kernel_launch(void* const* d_in, const int* in_sizes, int n_in,
                              void* d_out, int out_size, void* d_ws, size_t ws_size,
                              hipStream_t stream)
{
    (void)in_sizes; (void)n_in; (void)out_size;

    const float* x      = (const float*)d_in[0];
    const float* n1g    = (const float*)d_in[1];
    const float* n1b    = (const float*)d_in[2];
    const float* qkv_w  = (const float*)d_in[3];
    const float* qkv_b  = (const float*)d_in[4];
    const float* proj_w = (const float*)d_in[5];
    const float* proj_b = (const float*)d_in[6];
    const float* rpb    = (const float*)d_in[7];
    const float* n2g    = (const float*)d_in[8];
    const float* n2b    = (const float*)d_in[9];
    const float* fc1_w  = (const float*)d_in[10];
    const float* fc1_b  = (const float*)d_in[11];
    const float* fc2_w  = (const float*)d_in[12];
    const float* fc2_b  = (const float*)d_in[13];

    char* ws = (char*)d_ws;

    const size_t yb_sz = (size_t)M_ * 128 * 2;               // 51,380,224 (bf16 y)
    const size_t w_sz  = (size_t)(128 * 384 + 128 * 128 + 128 * 512 + 512 * 128) * 2;
    const size_t need  = yb_sz + w_sz;                       // ~51.8 MB

    if (need > ws_size) {
        sentinel_kernel<<<1, 256, 0, stream>>>((float*)d_out);
        return;
    }

    bf16_t* yb      = (bf16_t*)ws;
    bf16_t* qkv_wt  = (bf16_t*)(ws + yb_sz);
    bf16_t* proj_wt = qkv_wt + 128 * 384;
    bf16_t* fc1_wt  = proj_wt + 128 * 128;
    bf16_t* fc2_wt  = fc1_wt + 128 * 512;

    transpose_w<<<(128 * 384 + 255) / 256, 256, 0, stream>>>(qkv_w, qkv_wt, 128, 384);
    transpose_w<<<(128 * 128 + 255) / 256, 256, 0, stream>>>(proj_w, proj_wt, 128, 128);
    transpose_w<<<(128 * 512 + 255) / 256, 256, 0, stream>>>(fc1_w, fc1_wt, 128, 512);
    transpose_w<<<(512 * 128 + 255) / 256, 256, 0, stream>>>(fc2_w, fc2_wt, 512, 128);

    // LN1 + qkv + attention + proj + window-reverse + residual -> bf16 y
    swin_fused<<<NWIN, 256, 0, stream>>>(x, n1g, n1b, qkv_wt, qkv_b, rpb,
                                         proj_wt, proj_b, yb);
    // LN2 + fc1 + GELU + fc2 + residual -> f32 d_out
    mlp_fused<<<M_ / 256, 512, 0, stream>>>(
        yb, n2g, n2b, fc1_wt, fc1_b, fc2_wt, fc2_b, (float*)d_out);
}